// Round 2
// baseline (735.925 us; speedup 1.0000x reference)
//
#include <hip/hip_runtime.h>

#define HW    36864
#define NB    4
#define NCH   256
#define CIN   64
#define CB    16
#define NPIX  (NB*HW)          // 147456
#define DELTA 1e-4f

struct FlagEntry {
  unsigned pix;
  unsigned char cnt, need, r0, r1;   // r0 = full-f64-redo flag
  unsigned char ks[8];
};                              // 16 B

// ---------------- sorting networks (values only, fully unrolled) -------------

template<bool ASC>
__device__ __forceinline__ void bitonic16(float* v) {
  #pragma unroll
  for (int K = 2; K <= 16; K <<= 1) {
    #pragma unroll
    for (int J = K >> 1; J > 0; J >>= 1) {
      #pragma unroll
      for (int i = 0; i < 16; ++i) {
        int l = i ^ J;
        if (l > i) {
          bool up = (((i & K) == 0) == ASC);
          float a = v[i], b = v[l];
          float lo = fminf(a, b), hi = fmaxf(a, b);
          v[i] = up ? lo : hi;
          v[l] = up ? hi : lo;
        }
      }
    }
  }
}

__device__ __forceinline__ void bmerge16_desc(float* v) {
  #pragma unroll
  for (int J = 8; J > 0; J >>= 1) {
    #pragma unroll
    for (int i = 0; i < 16; ++i) {
      int l = i ^ J;
      if (l > i) {
        float a = v[i], b = v[l];
        float lo = fminf(a, b), hi = fmaxf(a, b);
        v[i] = hi; v[l] = lo;
      }
    }
  }
}

// ---------------- GEMV chunk: m[kk] = dot(feat, w_mask[k0+kk][:]) ------------
// Bitwise-identical between pass1 and pass2 (same inlined code, explicit fmaf).

__device__ __forceinline__ void gemv_chunk(const float* lwm, int k0,
    const float* f0, const float* f1, float* m0, float* m1)
{
  #pragma unroll
  for (int kk = 0; kk < 16; ++kk) {
    const float* r = lwm + (k0 + kk) * CB;
    float4 a = *(const float4*)(r);
    float4 b = *(const float4*)(r + 4);
    float4 c = *(const float4*)(r + 8);
    float4 d = *(const float4*)(r + 12);
    {
      float sA = fmaf(f0[3],  a.w, fmaf(f0[2],  a.z, fmaf(f0[1],  a.y, f0[0]  * a.x)));
      float sB = fmaf(f0[7],  b.w, fmaf(f0[6],  b.z, fmaf(f0[5],  b.y, f0[4]  * b.x)));
      float sC = fmaf(f0[11], c.w, fmaf(f0[10], c.z, fmaf(f0[9],  c.y, f0[8]  * c.x)));
      float sD = fmaf(f0[15], d.w, fmaf(f0[14], d.z, fmaf(f0[13], d.y, f0[12] * d.x)));
      m0[kk] = (sA + sB) + (sC + sD);
    }
    {
      float sA = fmaf(f1[3],  a.w, fmaf(f1[2],  a.z, fmaf(f1[1],  a.y, f1[0]  * a.x)));
      float sB = fmaf(f1[7],  b.w, fmaf(f1[6],  b.z, fmaf(f1[5],  b.y, f1[4]  * b.x)));
      float sC = fmaf(f1[11], c.w, fmaf(f1[10], c.z, fmaf(f1[9],  c.y, f1[8]  * c.x)));
      float sD = fmaf(f1[15], d.w, fmaf(f1[14], d.z, fmaf(f1[13], d.y, f1[12] * d.x)));
      m1[kk] = (sA + sB) + (sC + sD);
    }
  }
}

// ---------------- K0: zero flag counter --------------------------------------

__global__ void k0_zero(unsigned* flagcnt) { *flagcnt = 0u; }

// ---------------- K1: 1x1 conv (64->16) + f64 stats partials -----------------

__global__ __launch_bounds__(64) void k1_conv(
    const float* __restrict__ bfeat, const float* __restrict__ wb,
    const float* __restrict__ bb, float* __restrict__ xout,
    double* __restrict__ part)
{
  __shared__ float wbT[CIN][CB];
  const int t = threadIdx.x;
  for (int i = t; i < CIN*CB; i += 64) {
    int o = i >> 6, c = i & 63;
    wbT[c][o] = wb[i];
  }
  __syncthreads();
  float bias[CB];
  #pragma unroll
  for (int o = 0; o < CB; ++o) bias[o] = bb[o];

  const int blk = blockIdx.x;
  const int b = blk / 144, seg = blk % 144;
  const float* bfb = bfeat + (size_t)b * CIN * HW + seg * 256;
  float* xb = xout + (size_t)b * CB * HW + seg * 256;

  float acc[4][CB];
  #pragma unroll
  for (int i = 0; i < 4; ++i)
    #pragma unroll
    for (int o = 0; o < CB; ++o) acc[i][o] = bias[o];

  for (int c = 0; c < CIN; ++c) {
    float v0 = bfb[(size_t)c*HW + t];
    float v1 = bfb[(size_t)c*HW + 64 + t];
    float v2 = bfb[(size_t)c*HW + 128 + t];
    float v3 = bfb[(size_t)c*HW + 192 + t];
    #pragma unroll
    for (int o4 = 0; o4 < 4; ++o4) {
      float4 w4 = *(const float4*)&wbT[c][o4*4];
      acc[0][o4*4+0] = fmaf(v0, w4.x, acc[0][o4*4+0]);
      acc[0][o4*4+1] = fmaf(v0, w4.y, acc[0][o4*4+1]);
      acc[0][o4*4+2] = fmaf(v0, w4.z, acc[0][o4*4+2]);
      acc[0][o4*4+3] = fmaf(v0, w4.w, acc[0][o4*4+3]);
      acc[1][o4*4+0] = fmaf(v1, w4.x, acc[1][o4*4+0]);
      acc[1][o4*4+1] = fmaf(v1, w4.y, acc[1][o4*4+1]);
      acc[1][o4*4+2] = fmaf(v1, w4.z, acc[1][o4*4+2]);
      acc[1][o4*4+3] = fmaf(v1, w4.w, acc[1][o4*4+3]);
      acc[2][o4*4+0] = fmaf(v2, w4.x, acc[2][o4*4+0]);
      acc[2][o4*4+1] = fmaf(v2, w4.y, acc[2][o4*4+1]);
      acc[2][o4*4+2] = fmaf(v2, w4.z, acc[2][o4*4+2]);
      acc[2][o4*4+3] = fmaf(v2, w4.w, acc[2][o4*4+3]);
      acc[3][o4*4+0] = fmaf(v3, w4.x, acc[3][o4*4+0]);
      acc[3][o4*4+1] = fmaf(v3, w4.y, acc[3][o4*4+1]);
      acc[3][o4*4+2] = fmaf(v3, w4.z, acc[3][o4*4+2]);
      acc[3][o4*4+3] = fmaf(v3, w4.w, acc[3][o4*4+3]);
    }
  }

  double s[CB], sq[CB];
  #pragma unroll
  for (int o = 0; o < CB; ++o) { s[o] = 0.0; sq[o] = 0.0; }
  #pragma unroll
  for (int i = 0; i < 4; ++i)
    #pragma unroll
    for (int o = 0; o < CB; ++o) {
      float v = acc[i][o];
      xb[(size_t)o*HW + i*64 + t] = v;
      double dv = (double)v;
      s[o] += dv; sq[o] += dv*dv;
    }
  #pragma unroll
  for (int o = 0; o < CB; ++o) {
    double a = s[o], q = sq[o];
    for (int off = 32; off; off >>= 1) { a += __shfl_xor(a, off); q += __shfl_xor(q, off); }
    if (t == 0) { part[(size_t)blk*32 + o] = a; part[(size_t)blk*32 + CB + o] = q; }
  }
}

// ---------------- K1b: finalize BN stats -------------------------------------

__global__ __launch_bounds__(64) void k1b_stats(
    const double* __restrict__ part, const float* __restrict__ gam,
    const float* __restrict__ bet, double* __restrict__ st64, float* __restrict__ st32)
{
  __shared__ double sh[32];
  const int t = threadIdx.x;
  if (t < 32) {
    double a = 0.0;
    #pragma unroll 8
    for (int i = 0; i < 576; ++i) a += part[(size_t)i*32 + t];
    sh[t] = a;
  }
  __syncthreads();
  if (t < CB) {
    const double N = (double)NPIX;
    double mean = sh[t] / N;
    double var  = sh[16+t] / N - mean*mean;
    double rstd = 1.0 / sqrt(var + 1e-5);
    double scl = (double)gam[t] * rstd;
    double sft = (double)bet[t] - mean*scl;
    st64[t] = scl; st64[CB+t] = sft;
    st32[t] = (float)scl; st32[CB+t] = (float)sft;
  }
}

// ---------------- K2: main per-pixel kernel ----------------------------------

__device__ __forceinline__ void k2_epilogue(int b, int p, int pxl,
    int selN, int nearN, int nselN,
    float* lcw, unsigned char* lidx, unsigned char* lnear,
    unsigned* cidx, float* cw, unsigned* flagcnt, FlagEntry* entries)
{
  int start = selN < 16 ? selN : 16;
  for (int j = start; j < 16; ++j) { lcw[pxl*16 + j] = 0.f; lidx[pxl*16 + j] = 0; }
  unsigned g = (unsigned)(b*HW + p);
  uint4 iv = *(uint4*)&lidx[pxl*16];
  ((uint4*)cidx)[g] = iv;
  float4* cwq = (float4*)cw;
  #pragma unroll
  for (int q = 0; q < 4; ++q) cwq[(size_t)g*4 + q] = *(float4*)&lcw[pxl*16 + q*4];
  bool flag = (nearN > 1) || (selN != 16);
  if (flag) {
    unsigned slot = atomicAdd(flagcnt, 1u);
    FlagEntry e;
    e.pix = g;
    int cnt = nearN < 8 ? nearN : 8;
    e.cnt = (unsigned char)cnt;
    int nsure = selN - nselN;
    int need = 16 - nsure;
    if (need < 0) need = 0;
    if (need > cnt) need = cnt;
    e.need = (unsigned char)need;
    e.r0 = (nearN > 8) ? 1 : 0;   // full f64 redo required
    e.r1 = 0;
    #pragma unroll
    for (int j = 0; j < 8; ++j) e.ks[j] = (j < cnt) ? lnear[pxl*8 + j] : 0;
    entries[slot] = e;
  }
}

__global__ __launch_bounds__(64) void k2_main(
    const float* __restrict__ x, const float* __restrict__ wmg,
    const float* __restrict__ st32, float* __restrict__ msp,
    unsigned* __restrict__ cidx, float* __restrict__ cw,
    unsigned* __restrict__ flagcnt, FlagEntry* __restrict__ entries)
{
  __shared__ float lwm[NCH*CB];
  __shared__ float lcw[128*16];
  __shared__ __align__(16) unsigned char lidx[128*16];
  __shared__ unsigned char lnear[128*8];
  const int t = threadIdx.x;
  for (int i = t; i < NCH*CB; i += 64) lwm[i] = wmg[i];
  __syncthreads();

  const int blk = blockIdx.x;
  const int b = blk / 288, seg = blk % 288;
  const int p0 = seg*128 + t, p1 = p0 + 64;

  float sc[CB], sf[CB];
  #pragma unroll
  for (int o = 0; o < CB; ++o) { sc[o] = st32[o]; sf[o] = st32[CB+o]; }
  const float* xb = x + (size_t)b*CB*HW;
  float f0[CB], f1[CB];
  #pragma unroll
  for (int o = 0; o < CB; ++o) {
    f0[o] = fmaxf(0.f, fmaf(xb[(size_t)o*HW + p0], sc[o], sf[o]));
    f1[o] = fmaxf(0.f, fmaf(xb[(size_t)o*HW + p1], sc[o], sf[o]));
  }

  // ---- pass 1: streaming top-16 (values only) ----
  float T0a[16], T1a[16];
  {
    float m0[16], m1[16];
    gemv_chunk(lwm, 0, f0, f1, m0, m1);
    bitonic16<false>(m0); bitonic16<false>(m1);
    #pragma unroll
    for (int i = 0; i < 16; ++i) { T0a[i] = m0[i]; T1a[i] = m1[i]; }
  }
  for (int ch = 1; ch < 16; ++ch) {
    float m0[16], m1[16];
    gemv_chunk(lwm, ch*16, f0, f1, m0, m1);
    bitonic16<true>(m0); bitonic16<true>(m1);
    #pragma unroll
    for (int i = 0; i < 16; ++i) { T0a[i] = fmaxf(T0a[i], m0[i]); T1a[i] = fmaxf(T1a[i], m1[i]); }
    bmerge16_desc(T0a); bmerge16_desc(T1a);
  }
  const float tau0 = T0a[15], top0 = T0a[0];
  const float tau1 = T1a[15], top1 = T1a[0];
  float Z0 = 0.f, Z1 = 0.f;
  #pragma unroll
  for (int i = 0; i < 16; ++i) { Z0 += __expf(T0a[i]-top0); Z1 += __expf(T1a[i]-top1); }
  const float iZ0 = 1.f/Z0, iZ1 = 1.f/Z1;

  // ---- pass 2: recompute (bitwise identical), select, write dense + compact ----
  int sel0 = 0, near0 = 0, nsel0 = 0, sel1 = 0, near1 = 0, nsel1 = 0;
  float* mspb = msp + (size_t)b*NCH*HW;
  for (int ch = 0; ch < 16; ++ch) {
    float m0[16], m1[16];
    gemv_chunk(lwm, ch*16, f0, f1, m0, m1);
    #pragma unroll
    for (int kk = 0; kk < 16; ++kk) {
      const int k = ch*16 + kk;
      {
        const float v = m0[kk];
        const bool s = (v >= tau0);
        const bool nr = (fabsf(v - tau0) <= DELTA);
        float wv = 0.f;
        if (s) wv = __expf(v - top0) * iZ0;
        mspb[(size_t)k*HW + p0] = wv;
        if (s) { if (sel0 < 16) { lcw[t*16 + sel0] = wv; lidx[t*16 + sel0] = (unsigned char)k; } ++sel0; if (nr) ++nsel0; }
        if (nr) { if (near0 < 8) lnear[t*8 + near0] = (unsigned char)k; ++near0; }
      }
      {
        const float v = m1[kk];
        const bool s = (v >= tau1);
        const bool nr = (fabsf(v - tau1) <= DELTA);
        float wv = 0.f;
        if (s) wv = __expf(v - top1) * iZ1;
        mspb[(size_t)k*HW + p1] = wv;
        if (s) { if (sel1 < 16) { lcw[(t+64)*16 + sel1] = wv; lidx[(t+64)*16 + sel1] = (unsigned char)k; } ++sel1; if (nr) ++nsel1; }
        if (nr) { if (near1 < 8) lnear[(t+64)*8 + near1] = (unsigned char)k; ++near1; }
      }
    }
  }
  k2_epilogue(b, p0, t,      sel0, near0, nsel0, lcw, lidx, lnear, cidx, cw, flagcnt, entries);
  k2_epilogue(b, p1, t + 64, sel1, near1, nsel1, lcw, lidx, lnear, cidx, cw, flagcnt, entries);
}

// ---------------- K2b: fixup for near-boundary pixels ------------------------
// Light path (nearN<=8): f64 re-rank of near colors + weight transfer.
// Full path (nearN>8, e.g. all-tie rows): complete per-pixel f64 recompute.

__global__ __launch_bounds__(64) void k2b_fix(
    const float* __restrict__ bfeat, const float* __restrict__ wb,
    const float* __restrict__ bb, const float* __restrict__ wmg,
    const double* __restrict__ st64,
    const unsigned* __restrict__ flagcnt, const FlagEntry* __restrict__ entries,
    float* __restrict__ msp, unsigned* __restrict__ cidx, float* __restrict__ cw)
{
  const unsigned n = *flagcnt;
  const unsigned i = blockIdx.x*64u + threadIdx.x;
  if (i >= n) return;
  FlagEntry e = entries[i];
  const int b = (int)(e.pix / HW), p = (int)(e.pix % HW);

  // f64 feature recompute (shared by both paths)
  double xx[CB];
  #pragma unroll
  for (int o = 0; o < CB; ++o) xx[o] = (double)bb[o];
  const float* bfb = bfeat + (size_t)b*CIN*HW;
  for (int c = 0; c < CIN; ++c) {
    const double v = (double)bfb[(size_t)c*HW + p];
    #pragma unroll
    for (int o = 0; o < CB; ++o) xx[o] = fma(v, (double)wb[o*CIN + c], xx[o]);
  }
  double ft[CB];
  #pragma unroll
  for (int o = 0; o < CB; ++o) ft[o] = fmax(0.0, xx[o]*st64[o] + st64[CB+o]);

  float* mb = msp + (size_t)b*NCH*HW;
  unsigned char* cb_ = (unsigned char*)cidx + (size_t)e.pix*16;
  float* cwp = cw + (size_t)e.pix*16;

  if (e.r0) {
    // ---- full f64 redo: exact top-16 with (value desc, index asc) tie-break ----
    double tv[16]; int ti[16];
    #pragma unroll
    for (int j = 0; j < 16; ++j) { tv[j] = -1.0e300; ti[j] = 1 << 20; }
    for (int k = 0; k < NCH; ++k) {
      double m = 0.0;
      #pragma unroll
      for (int c = 0; c < CB; ++c) m = fma(ft[c], (double)wmg[k*CB + c], m);
      if (m > tv[15] || (m == tv[15] && k < ti[15])) {
        int pos = 15;
        while (pos > 0 && (m > tv[pos-1] || (m == tv[pos-1] && k < ti[pos-1]))) {
          tv[pos] = tv[pos-1]; ti[pos] = ti[pos-1]; --pos;
        }
        tv[pos] = m; ti[pos] = k;
      }
    }
    double top = tv[0], Z = 0.0, wv64[16];
    #pragma unroll
    for (int j = 0; j < 16; ++j) { wv64[j] = exp(tv[j] - top); Z += wv64[j]; }
    double iZ = 1.0 / Z;
    #pragma unroll
    for (int j = 0; j < 4; ++j) ((unsigned*)cb_)[j] = 0u;
    #pragma unroll
    for (int j = 0; j < 16; ++j) cwp[j] = 0.f;
    int oc = 0;
    for (int k = 0; k < NCH; ++k) {
      float w = 0.f;
      #pragma unroll
      for (int j = 0; j < 16; ++j) if (ti[j] == k) w = (float)(wv64[j] * iZ);
      mb[(size_t)k*HW + p] = w;
      if (w != 0.f && oc < 16) { cb_[oc] = (unsigned char)k; cwp[oc] = w; ++oc; }
    }
    return;
  }

  // ---- light path ----
  const int cnt = (e.cnt > 8) ? 8 : (int)e.cnt;
  int need = (int)e.need; if (need > cnt) need = cnt;

  int kr[8]; double m64[8]; float wold[8];
  #pragma unroll
  for (int j = 0; j < 8; ++j) {
    kr[j] = (j < cnt) ? (int)e.ks[j] : 0;
    double a = 0.0;
    if (j < cnt) {
      #pragma unroll
      for (int c = 0; c < CB; ++c) a = fma(ft[c], (double)wmg[kr[j]*CB + c], a);
    }
    m64[j] = a;
    wold[j] = (j < cnt) ? mb[(size_t)kr[j]*HW + p] : 0.f;
  }
  int rank[8];
  #pragma unroll
  for (int j = 0; j < 8; ++j) {
    int r = 0;
    #pragma unroll
    for (int j2 = 0; j2 < 8; ++j2) {
      if (j2 < cnt && j2 != j) {
        bool gt = (m64[j2] > m64[j]) || (m64[j2] == m64[j] && kr[j2] < kr[j]);
        r += gt ? 1 : 0;
      }
    }
    rank[j] = (j < cnt) ? r : 99;
  }
  float ws_[8]; int nw = 0;
  for (int j = 0; j < 8; ++j) if (j < cnt && wold[j] > 0.f) { ws_[nw] = wold[j]; ++nw; }
  for (int a2 = 1; a2 < nw; ++a2) {
    float v = ws_[a2]; int q = a2;
    while (q > 0 && ws_[q-1] < v) { ws_[q] = ws_[q-1]; --q; }
    ws_[q] = v;
  }
  float wn[8];
  #pragma unroll
  for (int j = 0; j < 8; ++j) {
    float v = 0.f;
    if (j < cnt && rank[j] < need && rank[j] < nw) v = ws_[rank[j]];
    wn[j] = v;
    if (j < cnt) mb[(size_t)kr[j]*HW + p] = v;
  }
  // rebuild compact
  #pragma unroll
  for (int j = 0; j < 4; ++j) ((unsigned*)cb_)[j] = 0u;
  #pragma unroll
  for (int j = 0; j < 16; ++j) cwp[j] = 0.f;
  int oc = 0;
  for (int k = 0; k < NCH; ++k) {
    float v = mb[(size_t)k*HW + p];
    #pragma unroll
    for (int j = 0; j < 8; ++j) if (j < cnt && k == kr[j]) v = wn[j];
    if (v != 0.f && oc < 16) { cb_[oc] = (unsigned char)k; cwp[oc] = v; ++oc; }
  }
}

// ---------------- K3: num/den accumulation -----------------------------------

__global__ __launch_bounds__(256) void k3_accum(
    const uint4* __restrict__ cidx, const float4* __restrict__ cw4,
    const float* __restrict__ img, float* __restrict__ part)
{
  __shared__ float acc[1024];
  const int t = threadIdx.x, blk = blockIdx.x;
  for (int i = t; i < 1024; i += 256) acc[i] = 0.f;
  __syncthreads();
  const int b = blk / 16;
  const int base = (blk % 16) * 2304;
  const float* imb = img + (size_t)b*3*HW;
  for (int it = 0; it < 9; ++it) {
    int p = base + it*256 + t;
    int g = b*HW + p;
    uint4 iv = cidx[g];
    unsigned ivq[4] = {iv.x, iv.y, iv.z, iv.w};
    float r = imb[p], g_ = imb[HW + p], bl = imb[2*HW + p];
    #pragma unroll
    for (int q = 0; q < 4; ++q) {
      float4 wv = cw4[(size_t)g*4 + q];
      float wvv[4] = {wv.x, wv.y, wv.z, wv.w};
      #pragma unroll
      for (int u = 0; u < 4; ++u) {
        int k = (int)((ivq[q] >> (8*u)) & 255u);
        float wgt = wvv[u];
        atomicAdd(&acc[k],       wgt * r);
        atomicAdd(&acc[256 + k], wgt * g_);
        atomicAdd(&acc[512 + k], wgt * bl);
        atomicAdd(&acc[768 + k], wgt);
      }
    }
  }
  __syncthreads();
  for (int i = t; i < 1024; i += 256) part[(size_t)blk*1024 + i] = acc[i];
}

// ---------------- K4: palette ------------------------------------------------

__global__ __launch_bounds__(256) void k4_pal(
    const float* __restrict__ part, float* __restrict__ out_pal)
{
  __shared__ float acc[1024];
  const int b = blockIdx.x, t = threadIdx.x;
  for (int s = t; s < 1024; s += 256) {
    float a = 0.f;
    #pragma unroll
    for (int i = 0; i < 16; ++i) a += part[(size_t)(b*16 + i)*1024 + s];
    acc[s] = a;
  }
  __syncthreads();
  for (int s = t; s < 768; s += 256) {
    int k = s & 255;
    float den = acc[768 + k] + 1e-8f;
    out_pal[(size_t)b*768 + s] = acc[s] / den;
  }
}

// ---------------- K5: recolored image ----------------------------------------

__global__ __launch_bounds__(256) void k5_img(
    const uint4* __restrict__ cidx, const float4* __restrict__ cw4,
    const float* __restrict__ pal, float* __restrict__ outimg)
{
  __shared__ float lp[768];
  const int t = threadIdx.x, blk = blockIdx.x;
  const int b = blk / 144;
  for (int i = t; i < 768; i += 256) lp[i] = pal[(size_t)b*768 + i];
  __syncthreads();
  const int p = (blk % 144) * 256 + t;
  const int g = b*HW + p;
  uint4 iv = cidx[g];
  unsigned ivq[4] = {iv.x, iv.y, iv.z, iv.w};
  float r = 0.f, g_ = 0.f, bl = 0.f;
  #pragma unroll
  for (int q = 0; q < 4; ++q) {
    float4 wv = cw4[(size_t)g*4 + q];
    float wvv[4] = {wv.x, wv.y, wv.z, wv.w};
    #pragma unroll
    for (int u = 0; u < 4; ++u) {
      int k = (int)((ivq[q] >> (8*u)) & 255u);
      float wgt = wvv[u];
      r  = fmaf(wgt, lp[k],       r);
      g_ = fmaf(wgt, lp[256 + k], g_);
      bl = fmaf(wgt, lp[512 + k], bl);
    }
  }
  float* ob = outimg + (size_t)b*3*HW;
  ob[p] = r; ob[HW + p] = g_; ob[2*HW + p] = bl;
}

// ---------------- launcher ---------------------------------------------------

extern "C" void kernel_launch(void* const* d_in, const int* in_sizes, int n_in,
                              void* d_out, int out_size, void* d_ws, size_t ws_size,
                              hipStream_t stream)
{
  const float* img   = (const float*)d_in[0];
  const float* bfeat = (const float*)d_in[1];
  const float* wb    = (const float*)d_in[2];
  const float* bb    = (const float*)d_in[3];
  const float* gam   = (const float*)d_in[4];
  const float* bet   = (const float*)d_in[5];
  const float* wm    = (const float*)d_in[6];

  float* out_img = (float*)d_out;                 // [4,3,192,192]
  float* out_msp = (float*)d_out + 442368;        // [4,256,192,192]
  float* out_pal = (float*)d_out + 38191104;      // [4,3,256,1,1]

  char* w = (char*)d_ws;
  float*     ws_x       = (float*)(w);                     // 9,437,184 B
  double*    ws_part    = (double*)(w + 9437184);          //   147,456 B
  double*    ws_st64    = (double*)(w + 9584640);          //       256 B
  float*     ws_st32    = (float*)(w + 9584896);           //       128 B
  unsigned*  ws_flagcnt = (unsigned*)(w + 9585152);        //       256 B pad
  FlagEntry* ws_entries = (FlagEntry*)(w + 9585408);       // 2,359,296 B
  unsigned*  ws_cidx    = (unsigned*)(w + 11944704);       // 2,359,296 B
  float*     ws_cw      = (float*)(w + 14304000);          // 9,437,184 B
  float*     ws_nd      = (float*)(w + 23741184);          //   262,144 B

  k0_zero<<<dim3(1), dim3(1), 0, stream>>>(ws_flagcnt);
  k1_conv<<<dim3(576), dim3(64), 0, stream>>>(bfeat, wb, bb, ws_x, ws_part);
  k1b_stats<<<dim3(1), dim3(64), 0, stream>>>(ws_part, gam, bet, ws_st64, ws_st32);
  k2_main<<<dim3(1152), dim3(64), 0, stream>>>(ws_x, wm, ws_st32, out_msp,
                                               ws_cidx, ws_cw, ws_flagcnt, ws_entries);
  k2b_fix<<<dim3(2304), dim3(64), 0, stream>>>(bfeat, wb, bb, wm, ws_st64,
                                               ws_flagcnt, ws_entries, out_msp, ws_cidx, ws_cw);
  k3_accum<<<dim3(64), dim3(256), 0, stream>>>((const uint4*)ws_cidx, (const float4*)ws_cw,
                                               img, ws_nd);
  k4_pal<<<dim3(4), dim3(256), 0, stream>>>(ws_nd, out_pal);
  k5_img<<<dim3(576), dim3(256), 0, stream>>>((const uint4*)ws_cidx, (const float4*)ws_cw,
                                              out_pal, out_img);
}

// Round 3
// 512.422 us; speedup vs baseline: 1.4362x; 1.4362x over previous
//
#include <hip/hip_runtime.h>

#define HW    36864
#define NB    4
#define NCH   256
#define CIN   64
#define CB    16
#define NPIX  (NB*HW)          // 147456
#define DELTA 1e-4f

struct FlagEntry {
  unsigned pix;
  unsigned char cnt, need, r0, r1;   // r0 = full-f64-redo flag
  unsigned char ks[8];
};                              // 16 B

// ---------------- sorting networks (values only, fully unrolled) -------------

template<bool ASC>
__device__ __forceinline__ void bitonic16(float* v) {
  #pragma unroll
  for (int K = 2; K <= 16; K <<= 1) {
    #pragma unroll
    for (int J = K >> 1; J > 0; J >>= 1) {
      #pragma unroll
      for (int i = 0; i < 16; ++i) {
        int l = i ^ J;
        if (l > i) {
          bool up = (((i & K) == 0) == ASC);
          float a = v[i], b = v[l];
          float lo = fminf(a, b), hi = fmaxf(a, b);
          v[i] = up ? lo : hi;
          v[l] = up ? hi : lo;
        }
      }
    }
  }
}

__device__ __forceinline__ void bmerge16_desc(float* v) {
  #pragma unroll
  for (int J = 8; J > 0; J >>= 1) {
    #pragma unroll
    for (int i = 0; i < 16; ++i) {
      int l = i ^ J;
      if (l > i) {
        float a = v[i], b = v[l];
        float lo = fminf(a, b), hi = fmaxf(a, b);
        v[i] = hi; v[l] = lo;
      }
    }
  }
}

// ---------------- GEMV chunk (1 pixel): m[kk] = dot(f, w_mask[k0+kk][:]) -----
// Bitwise-identical between pass1 and pass2 (same inlined code, explicit fmaf).
// wm reads are wave-uniform -> scalar loads, no LDS staging needed.

__device__ __forceinline__ void gemv1(const float* __restrict__ wm, int k0,
                                      const float* f, float* m)
{
  #pragma unroll
  for (int kk = 0; kk < 16; ++kk) {
    const float* r = wm + (k0 + kk) * CB;
    float4 a = *(const float4*)(r);
    float4 b = *(const float4*)(r + 4);
    float4 c = *(const float4*)(r + 8);
    float4 d = *(const float4*)(r + 12);
    float sA = fmaf(f[3],  a.w, fmaf(f[2],  a.z, fmaf(f[1],  a.y, f[0]  * a.x)));
    float sB = fmaf(f[7],  b.w, fmaf(f[6],  b.z, fmaf(f[5],  b.y, f[4]  * b.x)));
    float sC = fmaf(f[11], c.w, fmaf(f[10], c.z, fmaf(f[9],  c.y, f[8]  * c.x)));
    float sD = fmaf(f[15], d.w, fmaf(f[14], d.z, fmaf(f[13], d.y, f[12] * d.x)));
    m[kk] = (sA + sB) + (sC + sD);
  }
}

// ---------------- K0: zero flag counter --------------------------------------

__global__ void k0_zero(unsigned* flagcnt) { *flagcnt = 0u; }

// ---------------- K1: 1x1 conv (64->16) + f64 stats partials -----------------
// 576 blocks x 256 threads, 1 pixel/thread. Partial layout: [576][32] f64.

__global__ __launch_bounds__(256) void k1_conv(
    const float* __restrict__ bfeat, const float* __restrict__ wb,
    const float* __restrict__ bb, float* __restrict__ xout,
    double* __restrict__ part)
{
  __shared__ float wbT[CIN][CB];          // 4 KB
  __shared__ double redS[4][CB];          // per-wave partial sums
  __shared__ double redQ[4][CB];
  const int t = threadIdx.x;
  for (int i = t; i < CIN*CB; i += 256) {
    int o = i >> 6, c = i & 63;
    wbT[c][o] = wb[i];
  }
  __syncthreads();

  const int blk = blockIdx.x;             // 576
  const int b = blk / 144, seg = blk % 144;
  const int p = seg * 256 + t;
  const float* bfb = bfeat + (size_t)b * CIN * HW;

  float acc[CB];
  #pragma unroll
  for (int o = 0; o < CB; ++o) acc[o] = bb[o];

  for (int c = 0; c < CIN; ++c) {
    float v = bfb[(size_t)c*HW + p];
    #pragma unroll
    for (int o4 = 0; o4 < 4; ++o4) {
      float4 w4 = *(const float4*)&wbT[c][o4*4];
      acc[o4*4+0] = fmaf(v, w4.x, acc[o4*4+0]);
      acc[o4*4+1] = fmaf(v, w4.y, acc[o4*4+1]);
      acc[o4*4+2] = fmaf(v, w4.z, acc[o4*4+2]);
      acc[o4*4+3] = fmaf(v, w4.w, acc[o4*4+3]);
    }
  }

  float* xb = xout + (size_t)b * CB * HW;
  #pragma unroll
  for (int o = 0; o < CB; ++o) xb[(size_t)o*HW + p] = acc[o];

  const int wv = t >> 6, lane = t & 63;
  #pragma unroll
  for (int o = 0; o < CB; ++o) {
    double a = (double)acc[o], q = a*a;
    for (int off = 32; off; off >>= 1) { a += __shfl_xor(a, off); q += __shfl_xor(q, off); }
    if (lane == 0) { redS[wv][o] = a; redQ[wv][o] = q; }
  }
  __syncthreads();
  if (t < CB) {
    double a = redS[0][t] + redS[1][t] + redS[2][t] + redS[3][t];
    part[(size_t)blk*32 + t] = a;
  } else if (t < 32) {
    int o = t - CB;
    double q = redQ[0][o] + redQ[1][o] + redQ[2][o] + redQ[3][o];
    part[(size_t)blk*32 + t] = q;
  }
}

// ---------------- K1b: finalize BN stats -------------------------------------

__global__ __launch_bounds__(64) void k1b_stats(
    const double* __restrict__ part, const float* __restrict__ gam,
    const float* __restrict__ bet, double* __restrict__ st64, float* __restrict__ st32)
{
  __shared__ double sh[32];
  const int t = threadIdx.x;
  if (t < 32) {
    double a = 0.0;
    #pragma unroll 8
    for (int i = 0; i < 576; ++i) a += part[(size_t)i*32 + t];
    sh[t] = a;
  }
  __syncthreads();
  if (t < CB) {
    const double N = (double)NPIX;
    double mean = sh[t] / N;
    double var  = sh[16+t] / N - mean*mean;
    double rstd = 1.0 / sqrt(var + 1e-5);
    double scl = (double)gam[t] * rstd;
    double sft = (double)bet[t] - mean*scl;
    st64[t] = scl; st64[CB+t] = sft;
    st32[t] = (float)scl; st32[CB+t] = (float)sft;
  }
}

// ---------------- K2: main per-pixel kernel ----------------------------------
// 1152 blocks x 128 threads, 1 pixel/thread.

__device__ __forceinline__ void k2_epilogue(int b, int p, int pxl,
    int selN, int nearN, int nselN,
    float* lcw, unsigned char* lidx, unsigned char* lnear,
    unsigned* cidx, float* cw, unsigned* flagcnt, FlagEntry* entries)
{
  int start = selN < 16 ? selN : 16;
  for (int j = start; j < 16; ++j) { lcw[pxl*16 + j] = 0.f; lidx[pxl*16 + j] = 0; }
  unsigned g = (unsigned)(b*HW + p);
  uint4 iv = *(uint4*)&lidx[pxl*16];
  ((uint4*)cidx)[g] = iv;
  float4* cwq = (float4*)cw;
  #pragma unroll
  for (int q = 0; q < 4; ++q) cwq[(size_t)g*4 + q] = *(float4*)&lcw[pxl*16 + q*4];
  bool flag = (nearN > 1) || (selN != 16);
  if (flag) {
    unsigned slot = atomicAdd(flagcnt, 1u);
    FlagEntry e;
    e.pix = g;
    int cnt = nearN < 8 ? nearN : 8;
    e.cnt = (unsigned char)cnt;
    int nsure = selN - nselN;
    int need = 16 - nsure;
    if (need < 0) need = 0;
    if (need > cnt) need = cnt;
    e.need = (unsigned char)need;
    e.r0 = (nearN > 8) ? 1 : 0;
    e.r1 = 0;
    #pragma unroll
    for (int j = 0; j < 8; ++j) e.ks[j] = (j < cnt) ? lnear[pxl*8 + j] : 0;
    entries[slot] = e;
  }
}

__global__ __launch_bounds__(128, 4) void k2_main(
    const float* __restrict__ x, const float* __restrict__ wmg,
    const float* __restrict__ st32, float* __restrict__ msp,
    unsigned* __restrict__ cidx, float* __restrict__ cw,
    unsigned* __restrict__ flagcnt, FlagEntry* __restrict__ entries)
{
  __shared__ float lcw[128*16];                       // 8 KB
  __shared__ __align__(16) unsigned char lidx[128*16]; // 2 KB
  __shared__ unsigned char lnear[128*8];              // 1 KB
  const int t = threadIdx.x;
  const int blk = blockIdx.x;                         // 1152
  const int b = blk / 288, seg = blk % 288;
  const int p = seg*128 + t;

  const float* xb = x + (size_t)b*CB*HW;
  float f[CB];
  #pragma unroll
  for (int o = 0; o < CB; ++o)
    f[o] = fmaxf(0.f, fmaf(xb[(size_t)o*HW + p], st32[o], st32[CB+o]));

  // ---- pass 1: streaming top-16 (values only) ----
  float T[16];
  {
    float m[16];
    gemv1(wmg, 0, f, m);
    bitonic16<false>(m);
    #pragma unroll
    for (int i = 0; i < 16; ++i) T[i] = m[i];
  }
  for (int ch = 1; ch < 16; ++ch) {
    float m[16];
    gemv1(wmg, ch*16, f, m);
    bitonic16<true>(m);
    #pragma unroll
    for (int i = 0; i < 16; ++i) T[i] = fmaxf(T[i], m[i]);
    bmerge16_desc(T);
  }
  const float tau = T[15], top = T[0];
  float Z = 0.f;
  #pragma unroll
  for (int i = 0; i < 16; ++i) Z += __expf(T[i]-top);
  const float iZ = 1.f/Z;

  // ---- pass 2: recompute (bitwise identical), select, write dense + compact ----
  int sel = 0, nearc = 0, nsel = 0;
  float* mspb = msp + (size_t)b*NCH*HW;
  for (int ch = 0; ch < 16; ++ch) {
    float m[16];
    gemv1(wmg, ch*16, f, m);
    #pragma unroll
    for (int kk = 0; kk < 16; ++kk) {
      const int k = ch*16 + kk;
      const float v = m[kk];
      const bool s = (v >= tau);
      const bool nr = (fabsf(v - tau) <= DELTA);
      float wv = 0.f;
      if (s) wv = __expf(v - top) * iZ;
      mspb[(size_t)k*HW + p] = wv;
      if (s) { if (sel < 16) { lcw[t*16 + sel] = wv; lidx[t*16 + sel] = (unsigned char)k; } ++sel; if (nr) ++nsel; }
      if (nr) { if (nearc < 8) lnear[t*8 + nearc] = (unsigned char)k; ++nearc; }
    }
  }
  k2_epilogue(b, p, t, sel, nearc, nsel, lcw, lidx, lnear, cidx, cw, flagcnt, entries);
}

// ---------------- K2b: fixup for near-boundary pixels ------------------------

__global__ __launch_bounds__(64) void k2b_fix(
    const float* __restrict__ bfeat, const float* __restrict__ wb,
    const float* __restrict__ bb, const float* __restrict__ wmg,
    const double* __restrict__ st64,
    const unsigned* __restrict__ flagcnt, const FlagEntry* __restrict__ entries,
    float* __restrict__ msp, unsigned* __restrict__ cidx, float* __restrict__ cw)
{
  const unsigned n = *flagcnt;
  const unsigned i = blockIdx.x*64u + threadIdx.x;
  if (i >= n) return;
  FlagEntry e = entries[i];
  const int b = (int)(e.pix / HW), p = (int)(e.pix % HW);

  double xx[CB];
  #pragma unroll
  for (int o = 0; o < CB; ++o) xx[o] = (double)bb[o];
  const float* bfb = bfeat + (size_t)b*CIN*HW;
  for (int c = 0; c < CIN; ++c) {
    const double v = (double)bfb[(size_t)c*HW + p];
    #pragma unroll
    for (int o = 0; o < CB; ++o) xx[o] = fma(v, (double)wb[o*CIN + c], xx[o]);
  }
  double ft[CB];
  #pragma unroll
  for (int o = 0; o < CB; ++o) ft[o] = fmax(0.0, xx[o]*st64[o] + st64[CB+o]);

  float* mb = msp + (size_t)b*NCH*HW;
  unsigned char* cb_ = (unsigned char*)cidx + (size_t)e.pix*16;
  float* cwp = cw + (size_t)e.pix*16;

  if (e.r0) {
    // full f64 redo: exact top-16 with (value desc, index asc) tie-break
    double tv[16]; int ti[16];
    #pragma unroll
    for (int j = 0; j < 16; ++j) { tv[j] = -1.0e300; ti[j] = 1 << 20; }
    for (int k = 0; k < NCH; ++k) {
      double m = 0.0;
      #pragma unroll
      for (int c = 0; c < CB; ++c) m = fma(ft[c], (double)wmg[k*CB + c], m);
      if (m > tv[15] || (m == tv[15] && k < ti[15])) {
        int pos = 15;
        while (pos > 0 && (m > tv[pos-1] || (m == tv[pos-1] && k < ti[pos-1]))) {
          tv[pos] = tv[pos-1]; ti[pos] = ti[pos-1]; --pos;
        }
        tv[pos] = m; ti[pos] = k;
      }
    }
    double top = tv[0], Z = 0.0, wv64[16];
    #pragma unroll
    for (int j = 0; j < 16; ++j) { wv64[j] = exp(tv[j] - top); Z += wv64[j]; }
    double iZ = 1.0 / Z;
    #pragma unroll
    for (int j = 0; j < 4; ++j) ((unsigned*)cb_)[j] = 0u;
    #pragma unroll
    for (int j = 0; j < 16; ++j) cwp[j] = 0.f;
    int oc = 0;
    for (int k = 0; k < NCH; ++k) {
      float w = 0.f;
      #pragma unroll
      for (int j = 0; j < 16; ++j) if (ti[j] == k) w = (float)(wv64[j] * iZ);
      mb[(size_t)k*HW + p] = w;
      if (w != 0.f && oc < 16) { cb_[oc] = (unsigned char)k; cwp[oc] = w; ++oc; }
    }
    return;
  }

  const int cnt = (e.cnt > 8) ? 8 : (int)e.cnt;
  int need = (int)e.need; if (need > cnt) need = cnt;

  int kr[8]; double m64[8]; float wold[8];
  #pragma unroll
  for (int j = 0; j < 8; ++j) {
    kr[j] = (j < cnt) ? (int)e.ks[j] : 0;
    double a = 0.0;
    if (j < cnt) {
      #pragma unroll
      for (int c = 0; c < CB; ++c) a = fma(ft[c], (double)wmg[kr[j]*CB + c], a);
    }
    m64[j] = a;
    wold[j] = (j < cnt) ? mb[(size_t)kr[j]*HW + p] : 0.f;
  }
  int rank[8];
  #pragma unroll
  for (int j = 0; j < 8; ++j) {
    int r = 0;
    #pragma unroll
    for (int j2 = 0; j2 < 8; ++j2) {
      if (j2 < cnt && j2 != j) {
        bool gt = (m64[j2] > m64[j]) || (m64[j2] == m64[j] && kr[j2] < kr[j]);
        r += gt ? 1 : 0;
      }
    }
    rank[j] = (j < cnt) ? r : 99;
  }
  float ws_[8]; int nw = 0;
  for (int j = 0; j < 8; ++j) if (j < cnt && wold[j] > 0.f) { ws_[nw] = wold[j]; ++nw; }
  for (int a2 = 1; a2 < nw; ++a2) {
    float v = ws_[a2]; int q = a2;
    while (q > 0 && ws_[q-1] < v) { ws_[q] = ws_[q-1]; --q; }
    ws_[q] = v;
  }
  float wn[8];
  #pragma unroll
  for (int j = 0; j < 8; ++j) {
    float v = 0.f;
    if (j < cnt && rank[j] < need && rank[j] < nw) v = ws_[rank[j]];
    wn[j] = v;
    if (j < cnt) mb[(size_t)kr[j]*HW + p] = v;
  }
  #pragma unroll
  for (int j = 0; j < 4; ++j) ((unsigned*)cb_)[j] = 0u;
  #pragma unroll
  for (int j = 0; j < 16; ++j) cwp[j] = 0.f;
  int oc = 0;
  for (int k = 0; k < NCH; ++k) {
    float v = mb[(size_t)k*HW + p];
    #pragma unroll
    for (int j = 0; j < 8; ++j) if (j < cnt && k == kr[j]) v = wn[j];
    if (v != 0.f && oc < 16) { cb_[oc] = (unsigned char)k; cwp[oc] = v; ++oc; }
  }
}

// ---------------- K3: num/den accumulation -----------------------------------
// 576 blocks x 256 threads, 256 pixels/block; partials [576][1024] f32.

__global__ __launch_bounds__(256) void k3_accum(
    const uint4* __restrict__ cidx, const float4* __restrict__ cw4,
    const float* __restrict__ img, float* __restrict__ part)
{
  __shared__ float acc[1024];
  const int t = threadIdx.x, blk = blockIdx.x;
  for (int i = t; i < 1024; i += 256) acc[i] = 0.f;
  __syncthreads();
  const int b = blk / 144;
  const int p = (blk % 144) * 256 + t;
  const float* imb = img + (size_t)b*3*HW;
  const int g = b*HW + p;
  uint4 iv = cidx[g];
  unsigned ivq[4] = {iv.x, iv.y, iv.z, iv.w};
  float r = imb[p], g_ = imb[HW + p], bl = imb[2*HW + p];
  #pragma unroll
  for (int q = 0; q < 4; ++q) {
    float4 wv = cw4[(size_t)g*4 + q];
    float wvv[4] = {wv.x, wv.y, wv.z, wv.w};
    #pragma unroll
    for (int u = 0; u < 4; ++u) {
      int k = (int)((ivq[q] >> (8*u)) & 255u);
      float wgt = wvv[u];
      atomicAdd(&acc[k],       wgt * r);
      atomicAdd(&acc[256 + k], wgt * g_);
      atomicAdd(&acc[512 + k], wgt * bl);
      atomicAdd(&acc[768 + k], wgt);
    }
  }
  __syncthreads();
  for (int i = t; i < 1024; i += 256) part[(size_t)blk*1024 + i] = acc[i];
}

// ---------------- K4: palette ------------------------------------------------

__global__ __launch_bounds__(256) void k4_pal(
    const float* __restrict__ part, float* __restrict__ out_pal)
{
  __shared__ float acc[1024];
  const int b = blockIdx.x, t = threadIdx.x;
  for (int s = t; s < 1024; s += 256) {
    float a = 0.f;
    for (int i = 0; i < 144; ++i) a += part[(size_t)(b*144 + i)*1024 + s];
    acc[s] = a;
  }
  __syncthreads();
  for (int s = t; s < 768; s += 256) {
    int k = s & 255;
    float den = acc[768 + k] + 1e-8f;
    out_pal[(size_t)b*768 + s] = acc[s] / den;
  }
}

// ---------------- K5: recolored image ----------------------------------------

__global__ __launch_bounds__(256) void k5_img(
    const uint4* __restrict__ cidx, const float4* __restrict__ cw4,
    const float* __restrict__ pal, float* __restrict__ outimg)
{
  __shared__ float lp[768];
  const int t = threadIdx.x, blk = blockIdx.x;
  const int b = blk / 144;
  for (int i = t; i < 768; i += 256) lp[i] = pal[(size_t)b*768 + i];
  __syncthreads();
  const int p = (blk % 144) * 256 + t;
  const int g = b*HW + p;
  uint4 iv = cidx[g];
  unsigned ivq[4] = {iv.x, iv.y, iv.z, iv.w};
  float r = 0.f, g_ = 0.f, bl = 0.f;
  #pragma unroll
  for (int q = 0; q < 4; ++q) {
    float4 wv = cw4[(size_t)g*4 + q];
    float wvv[4] = {wv.x, wv.y, wv.z, wv.w};
    #pragma unroll
    for (int u = 0; u < 4; ++u) {
      int k = (int)((ivq[q] >> (8*u)) & 255u);
      float wgt = wvv[u];
      r  = fmaf(wgt, lp[k],       r);
      g_ = fmaf(wgt, lp[256 + k], g_);
      bl = fmaf(wgt, lp[512 + k], bl);
    }
  }
  float* ob = outimg + (size_t)b*3*HW;
  ob[p] = r; ob[HW + p] = g_; ob[2*HW + p] = bl;
}

// ---------------- launcher ---------------------------------------------------

extern "C" void kernel_launch(void* const* d_in, const int* in_sizes, int n_in,
                              void* d_out, int out_size, void* d_ws, size_t ws_size,
                              hipStream_t stream)
{
  const float* img   = (const float*)d_in[0];
  const float* bfeat = (const float*)d_in[1];
  const float* wb    = (const float*)d_in[2];
  const float* bb    = (const float*)d_in[3];
  const float* gam   = (const float*)d_in[4];
  const float* bet   = (const float*)d_in[5];
  const float* wm    = (const float*)d_in[6];

  float* out_img = (float*)d_out;                 // [4,3,192,192]
  float* out_msp = (float*)d_out + 442368;        // [4,256,192,192]
  float* out_pal = (float*)d_out + 38191104;      // [4,3,256,1,1]

  char* w = (char*)d_ws;
  float*     ws_x       = (float*)(w);                     // 9,437,184 B (dead after k2 -> reused for k3 partials)
  double*    ws_part    = (double*)(w + 9437184);          //   147,456 B
  double*    ws_st64    = (double*)(w + 9584640);          //       256 B
  float*     ws_st32    = (float*)(w + 9584896);           //       128 B
  unsigned*  ws_flagcnt = (unsigned*)(w + 9585152);        //       256 B pad
  FlagEntry* ws_entries = (FlagEntry*)(w + 9585408);       // 2,359,296 B
  unsigned*  ws_cidx    = (unsigned*)(w + 11944704);       // 2,359,296 B
  float*     ws_cw      = (float*)(w + 14304000);          // 9,437,184 B
  float*     ws_nd      = ws_x;                            // 2,359,296 B (aliases ws_x, safe: x dead after k2)

  k0_zero<<<dim3(1), dim3(1), 0, stream>>>(ws_flagcnt);
  k1_conv<<<dim3(576), dim3(256), 0, stream>>>(bfeat, wb, bb, ws_x, ws_part);
  k1b_stats<<<dim3(1), dim3(64), 0, stream>>>(ws_part, gam, bet, ws_st64, ws_st32);
  k2_main<<<dim3(1152), dim3(128), 0, stream>>>(ws_x, wm, ws_st32, out_msp,
                                                ws_cidx, ws_cw, ws_flagcnt, ws_entries);
  k2b_fix<<<dim3(2304), dim3(64), 0, stream>>>(bfeat, wb, bb, wm, ws_st64,
                                               ws_flagcnt, ws_entries, out_msp, ws_cidx, ws_cw);
  k3_accum<<<dim3(576), dim3(256), 0, stream>>>((const uint4*)ws_cidx, (const float4*)ws_cw,
                                                img, ws_nd);
  k4_pal<<<dim3(4), dim3(256), 0, stream>>>(ws_nd, out_pal);
  k5_img<<<dim3(576), dim3(256), 0, stream>>>((const uint4*)ws_cidx, (const float4*)ws_cw,
                                              out_pal, out_img);
}

// Round 4
// 411.170 us; speedup vs baseline: 1.7898x; 1.2463x over previous
//
#include <hip/hip_runtime.h>

#define HW    36864
#define NB    4
#define NCH   256
#define CIN   64
#define CB    16
#define NPIX  (NB*HW)          // 147456
#define DELTA 1e-4f

struct FlagEntry {
  unsigned pix;
  unsigned char cnt, need, r0, r1;   // r0 = full-f64-redo flag
  unsigned char ks[8];
};                              // 16 B

// ---------------- sorting networks (values only, fully unrolled) -------------

template<bool ASC>
__device__ __forceinline__ void bitonic16(float* v) {
  #pragma unroll
  for (int K = 2; K <= 16; K <<= 1) {
    #pragma unroll
    for (int J = K >> 1; J > 0; J >>= 1) {
      #pragma unroll
      for (int i = 0; i < 16; ++i) {
        int l = i ^ J;
        if (l > i) {
          bool up = (((i & K) == 0) == ASC);
          float a = v[i], b = v[l];
          float lo = fminf(a, b), hi = fmaxf(a, b);
          v[i] = up ? lo : hi;
          v[l] = up ? hi : lo;
        }
      }
    }
  }
}

__device__ __forceinline__ void bmerge16_desc(float* v) {
  #pragma unroll
  for (int J = 8; J > 0; J >>= 1) {
    #pragma unroll
    for (int i = 0; i < 16; ++i) {
      int l = i ^ J;
      if (l > i) {
        float a = v[i], b = v[l];
        float lo = fminf(a, b), hi = fmaxf(a, b);
        v[i] = hi; v[l] = lo;
      }
    }
  }
}

// ---------------- GEMV chunk (1 pixel): m[kk] = dot(f, w_mask[k0+kk][:]) -----
// Bitwise-identical between pass1 and pass2 (same inlined code, explicit fmaf).

__device__ __forceinline__ void gemv1(const float* __restrict__ wm, int k0,
                                      const float* f, float* m)
{
  #pragma unroll
  for (int kk = 0; kk < 16; ++kk) {
    const float* r = wm + (k0 + kk) * CB;
    float4 a = *(const float4*)(r);
    float4 b = *(const float4*)(r + 4);
    float4 c = *(const float4*)(r + 8);
    float4 d = *(const float4*)(r + 12);
    float sA = fmaf(f[3],  a.w, fmaf(f[2],  a.z, fmaf(f[1],  a.y, f[0]  * a.x)));
    float sB = fmaf(f[7],  b.w, fmaf(f[6],  b.z, fmaf(f[5],  b.y, f[4]  * b.x)));
    float sC = fmaf(f[11], c.w, fmaf(f[10], c.z, fmaf(f[9],  c.y, f[8]  * c.x)));
    float sD = fmaf(f[15], d.w, fmaf(f[14], d.z, fmaf(f[13], d.y, f[12] * d.x)));
    m[kk] = (sA + sB) + (sC + sD);
  }
}

// ---------------- K0: zero flag counter --------------------------------------

__global__ void k0_zero(unsigned* flagcnt) { *flagcnt = 0u; }

// ---------------- K1: 1x1 conv (64->16) + f64 stats partials -----------------

__global__ __launch_bounds__(256) void k1_conv(
    const float* __restrict__ bfeat, const float* __restrict__ wb,
    const float* __restrict__ bb, float* __restrict__ xout,
    double* __restrict__ part)
{
  __shared__ float wbT[CIN][CB];          // 4 KB
  __shared__ double redS[4][CB];
  __shared__ double redQ[4][CB];
  const int t = threadIdx.x;
  for (int i = t; i < CIN*CB; i += 256) {
    int o = i >> 6, c = i & 63;
    wbT[c][o] = wb[i];
  }
  __syncthreads();

  const int blk = blockIdx.x;             // 576
  const int b = blk / 144, seg = blk % 144;
  const int p = seg * 256 + t;
  const float* bfb = bfeat + (size_t)b * CIN * HW;

  float acc[CB];
  #pragma unroll
  for (int o = 0; o < CB; ++o) acc[o] = bb[o];

  for (int c = 0; c < CIN; ++c) {
    float v = bfb[(size_t)c*HW + p];
    #pragma unroll
    for (int o4 = 0; o4 < 4; ++o4) {
      float4 w4 = *(const float4*)&wbT[c][o4*4];
      acc[o4*4+0] = fmaf(v, w4.x, acc[o4*4+0]);
      acc[o4*4+1] = fmaf(v, w4.y, acc[o4*4+1]);
      acc[o4*4+2] = fmaf(v, w4.z, acc[o4*4+2]);
      acc[o4*4+3] = fmaf(v, w4.w, acc[o4*4+3]);
    }
  }

  float* xb = xout + (size_t)b * CB * HW;
  #pragma unroll
  for (int o = 0; o < CB; ++o) xb[(size_t)o*HW + p] = acc[o];

  const int wv = t >> 6, lane = t & 63;
  #pragma unroll
  for (int o = 0; o < CB; ++o) {
    double a = (double)acc[o], q = a*a;
    for (int off = 32; off; off >>= 1) { a += __shfl_xor(a, off); q += __shfl_xor(q, off); }
    if (lane == 0) { redS[wv][o] = a; redQ[wv][o] = q; }
  }
  __syncthreads();
  if (t < CB) {
    double a = redS[0][t] + redS[1][t] + redS[2][t] + redS[3][t];
    part[(size_t)blk*32 + t] = a;
  } else if (t < 32) {
    int o = t - CB;
    double q = redQ[0][o] + redQ[1][o] + redQ[2][o] + redQ[3][o];
    part[(size_t)blk*32 + t] = q;
  }
}

// ---------------- K1b: finalize BN stats -------------------------------------

__global__ __launch_bounds__(64) void k1b_stats(
    const double* __restrict__ part, const float* __restrict__ gam,
    const float* __restrict__ bet, double* __restrict__ st64, float* __restrict__ st32)
{
  __shared__ double sh[32];
  const int t = threadIdx.x;
  if (t < 32) {
    double a = 0.0;
    #pragma unroll 8
    for (int i = 0; i < 576; ++i) a += part[(size_t)i*32 + t];
    sh[t] = a;
  }
  __syncthreads();
  if (t < CB) {
    const double N = (double)NPIX;
    double mean = sh[t] / N;
    double var  = sh[16+t] / N - mean*mean;
    double rstd = 1.0 / sqrt(var + 1e-5);
    double scl = (double)gam[t] * rstd;
    double sft = (double)bet[t] - mean*scl;
    st64[t] = scl; st64[CB+t] = sft;
    st32[t] = (float)scl; st32[CB+t] = (float)sft;
  }
}

// ---------------- K2: main per-pixel kernel ----------------------------------

__device__ __forceinline__ void k2_epilogue(int b, int p, int pxl,
    int selN, int nearN, int nselN,
    float* lcw, unsigned char* lidx, unsigned char* lnear,
    unsigned* cidx, float* cw, unsigned* flagcnt, FlagEntry* entries)
{
  int start = selN < 16 ? selN : 16;
  for (int j = start; j < 16; ++j) { lcw[pxl*16 + j] = 0.f; lidx[pxl*16 + j] = 0; }
  unsigned g = (unsigned)(b*HW + p);
  uint4 iv = *(uint4*)&lidx[pxl*16];
  ((uint4*)cidx)[g] = iv;
  float4* cwq = (float4*)cw;
  #pragma unroll
  for (int q = 0; q < 4; ++q) cwq[(size_t)g*4 + q] = *(float4*)&lcw[pxl*16 + q*4];
  bool flag = (nearN > 1) || (selN != 16);
  if (flag) {
    unsigned slot = atomicAdd(flagcnt, 1u);
    FlagEntry e;
    e.pix = g;
    int cnt = nearN < 8 ? nearN : 8;
    e.cnt = (unsigned char)cnt;
    int nsure = selN - nselN;
    int need = 16 - nsure;
    if (need < 0) need = 0;
    if (need > cnt) need = cnt;
    e.need = (unsigned char)need;
    e.r0 = (nearN > 8 || selN != 16) ? 1 : 0;   // full f64 redo
    e.r1 = 0;
    #pragma unroll
    for (int j = 0; j < 8; ++j) e.ks[j] = (j < cnt) ? lnear[pxl*8 + j] : 0;
    entries[slot] = e;
  }
}

__global__ __launch_bounds__(128, 4) void k2_main(
    const float* __restrict__ x, const float* __restrict__ wmg,
    const float* __restrict__ st32, float* __restrict__ msp,
    unsigned* __restrict__ cidx, float* __restrict__ cw,
    unsigned* __restrict__ flagcnt, FlagEntry* __restrict__ entries)
{
  __shared__ float lcw[128*16];
  __shared__ __align__(16) unsigned char lidx[128*16];
  __shared__ unsigned char lnear[128*8];
  const int t = threadIdx.x;
  const int blk = blockIdx.x;                         // 1152
  const int b = blk / 288, seg = blk % 288;
  const int p = seg*128 + t;

  const float* xb = x + (size_t)b*CB*HW;
  float f[CB];
  #pragma unroll
  for (int o = 0; o < CB; ++o)
    f[o] = fmaxf(0.f, fmaf(xb[(size_t)o*HW + p], st32[o], st32[CB+o]));

  // ---- pass 1: streaming top-16 (values only) ----
  float T[16];
  {
    float m[16];
    gemv1(wmg, 0, f, m);
    bitonic16<false>(m);
    #pragma unroll
    for (int i = 0; i < 16; ++i) T[i] = m[i];
  }
  for (int ch = 1; ch < 16; ++ch) {
    float m[16];
    gemv1(wmg, ch*16, f, m);
    bitonic16<true>(m);
    #pragma unroll
    for (int i = 0; i < 16; ++i) T[i] = fmaxf(T[i], m[i]);
    bmerge16_desc(T);
  }
  const float tau = T[15], top = T[0];
  float Z = 0.f;
  #pragma unroll
  for (int i = 0; i < 16; ++i) Z += __expf(T[i]-top);
  const float iZ = 1.f/Z;

  // ---- pass 2: recompute (bitwise identical), select, write dense + compact ----
  int sel = 0, nearc = 0, nsel = 0;
  float* mspb = msp + (size_t)b*NCH*HW;
  for (int ch = 0; ch < 16; ++ch) {
    float m[16];
    gemv1(wmg, ch*16, f, m);
    #pragma unroll
    for (int kk = 0; kk < 16; ++kk) {
      const int k = ch*16 + kk;
      const float v = m[kk];
      const bool s = (v >= tau);
      const bool nr = (fabsf(v - tau) <= DELTA);
      float wv = 0.f;
      if (s) wv = __expf(v - top) * iZ;
      mspb[(size_t)k*HW + p] = wv;
      if (s) { if (sel < 16) { lcw[t*16 + sel] = wv; lidx[t*16 + sel] = (unsigned char)k; } ++sel; if (nr) ++nsel; }
      if (nr) { if (nearc < 8) lnear[t*8 + nearc] = (unsigned char)k; ++nearc; }
    }
  }
  k2_epilogue(b, p, t, sel, nearc, nsel, lcw, lidx, lnear, cidx, cw, flagcnt, entries);
}

// ---------------- K2b: fixup for near-boundary pixels ------------------------
// Light path (selN==16, nearN<=8): f64 re-rank + weight transfer, all compact
// bookkeeping in registers (no dense re-scan). Full path (r0): f64 redo.

__global__ __launch_bounds__(64) void k2b_fix(
    const float* __restrict__ bfeat, const float* __restrict__ wb,
    const float* __restrict__ bb, const float* __restrict__ wmg,
    const double* __restrict__ st64,
    const unsigned* __restrict__ flagcnt, const FlagEntry* __restrict__ entries,
    float* __restrict__ msp, unsigned* __restrict__ cidx, float* __restrict__ cw)
{
  const unsigned n = *flagcnt;
  const unsigned i = blockIdx.x*64u + threadIdx.x;
  if (i >= n) return;
  FlagEntry e = entries[i];
  const int b = (int)(e.pix / HW), p = (int)(e.pix % HW);

  // burst-load all 64 base features (all loads in flight at once)
  const float* bfb = bfeat + (size_t)b*CIN*HW;
  float vals[CIN];
  #pragma unroll
  for (int c = 0; c < CIN; ++c) vals[c] = bfb[(size_t)c*HW + p];

  // f64 conv + BN + ReLU
  double xx[CB];
  #pragma unroll
  for (int o = 0; o < CB; ++o) xx[o] = (double)bb[o];
  #pragma unroll 4
  for (int c = 0; c < CIN; ++c) {
    const double v = (double)vals[c];
    #pragma unroll
    for (int o = 0; o < CB; ++o) xx[o] = fma(v, (double)wb[o*CIN + c], xx[o]);
  }
  double ft[CB];
  #pragma unroll
  for (int o = 0; o < CB; ++o) ft[o] = fmax(0.0, xx[o]*st64[o] + st64[CB+o]);

  float* mb = msp + (size_t)b*NCH*HW;
  unsigned char* cb_ = (unsigned char*)cidx + (size_t)e.pix*16;
  float* cwp = cw + (size_t)e.pix*16;

  if (e.r0) {
    // full f64 redo: exact top-16 with (value desc, index asc) tie-break
    double tv[16]; int ti[16];
    #pragma unroll
    for (int j = 0; j < 16; ++j) { tv[j] = -1.0e300; ti[j] = 1 << 20; }
    for (int k = 0; k < NCH; ++k) {
      double m = 0.0;
      #pragma unroll
      for (int c = 0; c < CB; ++c) m = fma(ft[c], (double)wmg[k*CB + c], m);
      if (m > tv[15] || (m == tv[15] && k < ti[15])) {
        int pos = 15;
        while (pos > 0 && (m > tv[pos-1] || (m == tv[pos-1] && k < ti[pos-1]))) {
          tv[pos] = tv[pos-1]; ti[pos] = ti[pos-1]; --pos;
        }
        tv[pos] = m; ti[pos] = k;
      }
    }
    double top = tv[0], Z = 0.0, wv64[16];
    #pragma unroll
    for (int j = 0; j < 16; ++j) { wv64[j] = exp(tv[j] - top); Z += wv64[j]; }
    double iZ = 1.0 / Z;
    #pragma unroll
    for (int j = 0; j < 4; ++j) ((unsigned*)cb_)[j] = 0u;
    #pragma unroll
    for (int j = 0; j < 16; ++j) cwp[j] = 0.f;
    int oc = 0;
    for (int k = 0; k < NCH; ++k) {
      float w = 0.f;
      #pragma unroll
      for (int j = 0; j < 16; ++j) if (ti[j] == k) w = (float)(wv64[j] * iZ);
      mb[(size_t)k*HW + p] = w;
      if (w != 0.f && oc < 16) { cb_[oc] = (unsigned char)k; cwp[oc] = w; ++oc; }
    }
    return;
  }

  // ---- light path (selN==16 guaranteed, so compact list = full selected set) ----
  const int cnt = (e.cnt > 8) ? 8 : (int)e.cnt;
  int need = (int)e.need; if (need > cnt) need = cnt;

  // original compact list (ascending k, 16 valid entries)
  unsigned char kOrig[16]; float wOrig[16];
  #pragma unroll
  for (int j = 0; j < 16; ++j) kOrig[j] = cb_[j];
  #pragma unroll
  for (int j = 0; j < 16; ++j) wOrig[j] = cwp[j];

  int kr[8]; double m64[8]; float wold[8];
  #pragma unroll
  for (int j = 0; j < 8; ++j) {
    kr[j] = (j < cnt) ? (int)e.ks[j] : 0;
    double a = 0.0;
    if (j < cnt) {
      #pragma unroll
      for (int c = 0; c < CB; ++c) a = fma(ft[c], (double)wmg[kr[j]*CB + c], a);
    }
    m64[j] = a;
    float w = 0.f;
    if (j < cnt) {
      #pragma unroll
      for (int q = 0; q < 16; ++q)
        if ((int)kOrig[q] == kr[j] && wOrig[q] > 0.f) w = wOrig[q];
    }
    wold[j] = w;
  }
  int rank[8];
  #pragma unroll
  for (int j = 0; j < 8; ++j) {
    int r = 0;
    #pragma unroll
    for (int j2 = 0; j2 < 8; ++j2) {
      if (j2 < cnt && j2 != j) {
        bool gt = (m64[j2] > m64[j]) || (m64[j2] == m64[j] && kr[j2] < kr[j]);
        r += gt ? 1 : 0;
      }
    }
    rank[j] = (j < cnt) ? r : 99;
  }
  float ws_[8]; int nw = 0;
  for (int j = 0; j < 8; ++j) if (j < cnt && wold[j] > 0.f) { ws_[nw] = wold[j]; ++nw; }
  for (int a2 = 1; a2 < nw; ++a2) {
    float v = ws_[a2]; int q = a2;
    while (q > 0 && ws_[q-1] < v) { ws_[q] = ws_[q-1]; --q; }
    ws_[q] = v;
  }
  float wn[8];
  #pragma unroll
  for (int j = 0; j < 8; ++j) {
    float v = 0.f;
    if (j < cnt && rank[j] < need && rank[j] < nw) v = ws_[rank[j]];
    wn[j] = v;
    if (j < cnt) mb[(size_t)kr[j]*HW + p] = v;   // <=8 strided dense writes
  }

  // in-register merge rebuild of the compact list (no dense scan)
  unsigned char nk[16]; float nwv[16];
  int on = 0, ii = 0, jj = 0;
  while (ii < 16 || jj < cnt) {
    if (ii < 16 && wOrig[ii] <= 0.f) { ++ii; continue; }
    int ko = (ii < 16) ? (int)kOrig[ii] : (1 << 20);
    int kj = (jj < cnt) ? kr[jj] : (1 << 20);
    if (ko >= (1 << 20) && kj >= (1 << 20)) break;
    if (ko < kj) {
      if (on < 16) { nk[on] = (unsigned char)ko; nwv[on] = wOrig[ii]; ++on; }
      ++ii;
    } else if (kj < ko) {
      if (wn[jj] > 0.f && on < 16) { nk[on] = (unsigned char)kj; nwv[on] = wn[jj]; ++on; }
      ++jj;
    } else {
      if (wn[jj] > 0.f && on < 16) { nk[on] = (unsigned char)kj; nwv[on] = wn[jj]; ++on; }
      ++ii; ++jj;
    }
  }
  for (int j = on; j < 16; ++j) { nk[j] = 0; nwv[j] = 0.f; }
  #pragma unroll
  for (int q = 0; q < 4; ++q) {
    unsigned pk = (unsigned)nk[q*4] | ((unsigned)nk[q*4+1] << 8)
                | ((unsigned)nk[q*4+2] << 16) | ((unsigned)nk[q*4+3] << 24);
    ((unsigned*)cb_)[q] = pk;
  }
  #pragma unroll
  for (int j = 0; j < 16; ++j) cwp[j] = nwv[j];
}

// ---------------- K3: num/den accumulation -----------------------------------

__global__ __launch_bounds__(256) void k3_accum(
    const uint4* __restrict__ cidx, const float4* __restrict__ cw4,
    const float* __restrict__ img, float* __restrict__ part)
{
  __shared__ float acc[1024];
  const int t = threadIdx.x, blk = blockIdx.x;
  for (int i = t; i < 1024; i += 256) acc[i] = 0.f;
  __syncthreads();
  const int b = blk / 144;
  const int p = (blk % 144) * 256 + t;
  const float* imb = img + (size_t)b*3*HW;
  const int g = b*HW + p;
  uint4 iv = cidx[g];
  unsigned ivq[4] = {iv.x, iv.y, iv.z, iv.w};
  float r = imb[p], g_ = imb[HW + p], bl = imb[2*HW + p];
  #pragma unroll
  for (int q = 0; q < 4; ++q) {
    float4 wv = cw4[(size_t)g*4 + q];
    float wvv[4] = {wv.x, wv.y, wv.z, wv.w};
    #pragma unroll
    for (int u = 0; u < 4; ++u) {
      int k = (int)((ivq[q] >> (8*u)) & 255u);
      float wgt = wvv[u];
      atomicAdd(&acc[k],       wgt * r);
      atomicAdd(&acc[256 + k], wgt * g_);
      atomicAdd(&acc[512 + k], wgt * bl);
      atomicAdd(&acc[768 + k], wgt);
    }
  }
  __syncthreads();
  for (int i = t; i < 1024; i += 256) part[(size_t)blk*1024 + i] = acc[i];
}

// ---------------- K4: palette ------------------------------------------------

__global__ __launch_bounds__(256) void k4_pal(
    const float* __restrict__ part, float* __restrict__ out_pal)
{
  __shared__ float acc[1024];
  const int b = blockIdx.x, t = threadIdx.x;
  for (int s = t; s < 1024; s += 256) {
    float a = 0.f;
    for (int i = 0; i < 144; ++i) a += part[(size_t)(b*144 + i)*1024 + s];
    acc[s] = a;
  }
  __syncthreads();
  for (int s = t; s < 768; s += 256) {
    int k = s & 255;
    float den = acc[768 + k] + 1e-8f;
    out_pal[(size_t)b*768 + s] = acc[s] / den;
  }
}

// ---------------- K5: recolored image ----------------------------------------

__global__ __launch_bounds__(256) void k5_img(
    const uint4* __restrict__ cidx, const float4* __restrict__ cw4,
    const float* __restrict__ pal, float* __restrict__ outimg)
{
  __shared__ float lp[768];
  const int t = threadIdx.x, blk = blockIdx.x;
  const int b = blk / 144;
  for (int i = t; i < 768; i += 256) lp[i] = pal[(size_t)b*768 + i];
  __syncthreads();
  const int p = (blk % 144) * 256 + t;
  const int g = b*HW + p;
  uint4 iv = cidx[g];
  unsigned ivq[4] = {iv.x, iv.y, iv.z, iv.w};
  float r = 0.f, g_ = 0.f, bl = 0.f;
  #pragma unroll
  for (int q = 0; q < 4; ++q) {
    float4 wv = cw4[(size_t)g*4 + q];
    float wvv[4] = {wv.x, wv.y, wv.z, wv.w};
    #pragma unroll
    for (int u = 0; u < 4; ++u) {
      int k = (int)((ivq[q] >> (8*u)) & 255u);
      float wgt = wvv[u];
      r  = fmaf(wgt, lp[k],       r);
      g_ = fmaf(wgt, lp[256 + k], g_);
      bl = fmaf(wgt, lp[512 + k], bl);
    }
  }
  float* ob = outimg + (size_t)b*3*HW;
  ob[p] = r; ob[HW + p] = g_; ob[2*HW + p] = bl;
}

// ---------------- launcher ---------------------------------------------------

extern "C" void kernel_launch(void* const* d_in, const int* in_sizes, int n_in,
                              void* d_out, int out_size, void* d_ws, size_t ws_size,
                              hipStream_t stream)
{
  const float* img   = (const float*)d_in[0];
  const float* bfeat = (const float*)d_in[1];
  const float* wb    = (const float*)d_in[2];
  const float* bb    = (const float*)d_in[3];
  const float* gam   = (const float*)d_in[4];
  const float* bet   = (const float*)d_in[5];
  const float* wm    = (const float*)d_in[6];

  float* out_img = (float*)d_out;                 // [4,3,192,192]
  float* out_msp = (float*)d_out + 442368;        // [4,256,192,192]
  float* out_pal = (float*)d_out + 38191104;      // [4,3,256,1,1]

  char* w = (char*)d_ws;
  float*     ws_x       = (float*)(w);                     // 9,437,184 B (dead after k2 -> reused for k3 partials)
  double*    ws_part    = (double*)(w + 9437184);          //   147,456 B
  double*    ws_st64    = (double*)(w + 9584640);          //       256 B
  float*     ws_st32    = (float*)(w + 9584896);           //       128 B
  unsigned*  ws_flagcnt = (unsigned*)(w + 9585152);        //       256 B pad
  FlagEntry* ws_entries = (FlagEntry*)(w + 9585408);       // 2,359,296 B
  unsigned*  ws_cidx    = (unsigned*)(w + 11944704);       // 2,359,296 B
  float*     ws_cw      = (float*)(w + 14304000);          // 9,437,184 B
  float*     ws_nd      = ws_x;                            // aliases ws_x (x dead after k2)

  k0_zero<<<dim3(1), dim3(1), 0, stream>>>(ws_flagcnt);
  k1_conv<<<dim3(576), dim3(256), 0, stream>>>(bfeat, wb, bb, ws_x, ws_part);
  k1b_stats<<<dim3(1), dim3(64), 0, stream>>>(ws_part, gam, bet, ws_st64, ws_st32);
  k2_main<<<dim3(1152), dim3(128), 0, stream>>>(ws_x, wm, ws_st32, out_msp,
                                                ws_cidx, ws_cw, ws_flagcnt, ws_entries);
  k2b_fix<<<dim3(2304), dim3(64), 0, stream>>>(bfeat, wb, bb, wm, ws_st64,
                                               ws_flagcnt, ws_entries, out_msp, ws_cidx, ws_cw);
  k3_accum<<<dim3(576), dim3(256), 0, stream>>>((const uint4*)ws_cidx, (const float4*)ws_cw,
                                                img, ws_nd);
  k4_pal<<<dim3(4), dim3(256), 0, stream>>>(ws_nd, out_pal);
  k5_img<<<dim3(576), dim3(256), 0, stream>>>((const uint4*)ws_cidx, (const float4*)ws_cw,
                                              out_pal, out_img);
}

// Round 5
// 380.466 us; speedup vs baseline: 1.9343x; 1.0807x over previous
//
#include <hip/hip_runtime.h>

#define HW    36864
#define NB    4
#define NCH   256
#define CIN   64
#define CB    16
#define NPIX  (NB*HW)          // 147456
#define DELTA 1e-4f

typedef short bf16x8 __attribute__((ext_vector_type(8)));
typedef float f32x4  __attribute__((ext_vector_type(4)));

struct FlagEntry {
  unsigned pix;
  unsigned char cnt, need, r0, r1;   // r0 = full-f64-redo flag
  unsigned char ks[8];
};                              // 16 B

// ---------------- bf16 split helpers (RNE) -----------------------------------

__device__ __forceinline__ unsigned short bf16_rne(float x) {
  unsigned u = __float_as_uint(x);
  unsigned r = u + 0x7fffu + ((u >> 16) & 1u);
  return (unsigned short)(r >> 16);
}
__device__ __forceinline__ float bf16_tof(unsigned short h) {
  return __uint_as_float(((unsigned)h) << 16);
}

// ---------------- sorting networks (values only, fully unrolled) -------------

template<bool ASC>
__device__ __forceinline__ void bitonic16(float* v) {
  #pragma unroll
  for (int K = 2; K <= 16; K <<= 1) {
    #pragma unroll
    for (int J = K >> 1; J > 0; J >>= 1) {
      #pragma unroll
      for (int i = 0; i < 16; ++i) {
        int l = i ^ J;
        if (l > i) {
          bool up = (((i & K) == 0) == ASC);
          float a = v[i], b = v[l];
          float lo = fminf(a, b), hi = fmaxf(a, b);
          v[i] = up ? lo : hi;
          v[l] = up ? hi : lo;
        }
      }
    }
  }
}

__device__ __forceinline__ void bmerge16_desc(float* v) {
  #pragma unroll
  for (int J = 8; J > 0; J >>= 1) {
    #pragma unroll
    for (int i = 0; i < 16; ++i) {
      int l = i ^ J;
      if (l > i) {
        float a = v[i], b = v[l];
        float lo = fminf(a, b), hi = fmaxf(a, b);
        v[i] = hi; v[l] = lo;
      }
    }
  }
}

// ---------------- K0: zero flag counter --------------------------------------

__global__ void k0_zero(unsigned* flagcnt) { *flagcnt = 0u; }

// ---------------- K1: 1x1 conv (64->16) + f64 stats partials -----------------

__global__ __launch_bounds__(256) void k1_conv(
    const float* __restrict__ bfeat, const float* __restrict__ wb,
    const float* __restrict__ bb, float* __restrict__ xout,
    double* __restrict__ part)
{
  __shared__ float wbT[CIN][CB];          // 4 KB
  __shared__ double redS[4][CB];
  __shared__ double redQ[4][CB];
  const int t = threadIdx.x;
  for (int i = t; i < CIN*CB; i += 256) {
    int o = i >> 6, c = i & 63;
    wbT[c][o] = wb[i];
  }
  __syncthreads();

  const int blk = blockIdx.x;             // 576
  const int b = blk / 144, seg = blk % 144;
  const int p = seg * 256 + t;
  const float* bfb = bfeat + (size_t)b * CIN * HW;

  float acc[CB];
  #pragma unroll
  for (int o = 0; o < CB; ++o) acc[o] = bb[o];

  for (int c = 0; c < CIN; ++c) {
    float v = bfb[(size_t)c*HW + p];
    #pragma unroll
    for (int o4 = 0; o4 < 4; ++o4) {
      float4 w4 = *(const float4*)&wbT[c][o4*4];
      acc[o4*4+0] = fmaf(v, w4.x, acc[o4*4+0]);
      acc[o4*4+1] = fmaf(v, w4.y, acc[o4*4+1]);
      acc[o4*4+2] = fmaf(v, w4.z, acc[o4*4+2]);
      acc[o4*4+3] = fmaf(v, w4.w, acc[o4*4+3]);
    }
  }

  float* xb = xout + (size_t)b * CB * HW;
  #pragma unroll
  for (int o = 0; o < CB; ++o) xb[(size_t)o*HW + p] = acc[o];

  const int wv = t >> 6, lane = t & 63;
  #pragma unroll
  for (int o = 0; o < CB; ++o) {
    double a = (double)acc[o], q = a*a;
    for (int off = 32; off; off >>= 1) { a += __shfl_xor(a, off); q += __shfl_xor(q, off); }
    if (lane == 0) { redS[wv][o] = a; redQ[wv][o] = q; }
  }
  __syncthreads();
  if (t < CB) {
    double a = redS[0][t] + redS[1][t] + redS[2][t] + redS[3][t];
    part[(size_t)blk*32 + t] = a;
  } else if (t < 32) {
    int o = t - CB;
    double q = redQ[0][o] + redQ[1][o] + redQ[2][o] + redQ[3][o];
    part[(size_t)blk*32 + t] = q;
  }
}

// ---------------- K1b: finalize BN stats -------------------------------------

__global__ __launch_bounds__(64) void k1b_stats(
    const double* __restrict__ part, const float* __restrict__ gam,
    const float* __restrict__ bet, double* __restrict__ st64, float* __restrict__ st32)
{
  __shared__ double sh[32];
  const int t = threadIdx.x;
  if (t < 32) {
    double a = 0.0;
    #pragma unroll 8
    for (int i = 0; i < 576; ++i) a += part[(size_t)i*32 + t];
    sh[t] = a;
  }
  __syncthreads();
  if (t < CB) {
    const double N = (double)NPIX;
    double mean = sh[t] / N;
    double var  = sh[16+t] / N - mean*mean;
    double rstd = 1.0 / sqrt(var + 1e-5);
    double scl = (double)gam[t] * rstd;
    double sft = (double)bet[t] - mean*scl;
    st64[t] = scl; st64[CB+t] = sft;
    st32[t] = (float)scl; st32[CB+t] = (float)sft;
  }
}

// ---------------- K1c: build split-bf16 B fragments for MFMA -----------------
// Bfrag[v][ct][lane][8] shorts; v=0: [wh;wl], v=1: [wl;wh]. 32 KB total.

__global__ __launch_bounds__(256) void k1c_bfrag(
    const float* __restrict__ wm, short* __restrict__ bfrag)
{
  const int t = threadIdx.x;
  for (int e = t; e < 2048; e += 256) {       // (v, ct, lane)
    const int v = e >> 10, ct = (e >> 6) & 15, l = e & 63;
    const int n = l & 15, g = l >> 4;
    const int col = ct*16 + n;
    short out[8];
    #pragma unroll
    for (int j = 0; j < 8; ++j) {
      const int k = g*8 + j;
      const int kk = k & 15;
      const bool hi_half = (k < 16);
      float w = wm[col*CB + kk];
      unsigned short hb = bf16_rne(w);
      float res = w - bf16_tof(hb);
      unsigned short lb = bf16_rne(res);
      bool use_hi = ((v == 0) == hi_half);
      out[j] = (short)(use_hi ? hb : lb);
    }
    bf16x8 pk;
    #pragma unroll
    for (int j = 0; j < 8; ++j) pk[j] = out[j];
    *(bf16x8*)&bfrag[(size_t)e * 8] = pk;
  }
}

// ---------------- K2: main per-pixel kernel (MFMA + LDS m-tile) --------------
// 2304 blocks x 256 threads; 64 pixels/block; 72192 B dynamic LDS.

__device__ __forceinline__ void k2_epilogue(int b, int p, int pxl,
    int selN, int nearN, int nselN,
    float* lcw, unsigned char* lidx, unsigned char* lnear,
    unsigned* cidx, float* cw, unsigned* flagcnt, FlagEntry* entries)
{
  int start = selN < 16 ? selN : 16;
  for (int j = start; j < 16; ++j) { lcw[pxl*16 + j] = 0.f; lidx[pxl*16 + j] = 0; }
  unsigned g = (unsigned)(b*HW + p);
  uint4 iv = *(uint4*)&lidx[pxl*16];
  ((uint4*)cidx)[g] = iv;
  float4* cwq = (float4*)cw;
  #pragma unroll
  for (int q = 0; q < 4; ++q) cwq[(size_t)g*4 + q] = *(float4*)&lcw[pxl*16 + q*4];
  bool flag = (nearN > 1) || (selN != 16);
  if (flag) {
    unsigned slot = atomicAdd(flagcnt, 1u);
    FlagEntry e;
    e.pix = g;
    int cnt = nearN < 8 ? nearN : 8;
    e.cnt = (unsigned char)cnt;
    int nsure = selN - nselN;
    int need = 16 - nsure;
    if (need < 0) need = 0;
    if (need > cnt) need = cnt;
    e.need = (unsigned char)need;
    e.r0 = (nearN > 8 || selN != 16) ? 1 : 0;
    e.r1 = 0;
    #pragma unroll
    for (int j = 0; j < 8; ++j) e.ks[j] = (j < cnt) ? lnear[pxl*8 + j] : 0;
    entries[slot] = e;
  }
}

#define MSTRIDE 260

__global__ __launch_bounds__(256, 2) void k2_main(
    const float* __restrict__ x, const short* __restrict__ bfrag,
    const float* __restrict__ st32, float* __restrict__ msp,
    unsigned* __restrict__ cidx, float* __restrict__ cw,
    unsigned* __restrict__ flagcnt, FlagEntry* __restrict__ entries)
{
  extern __shared__ char smem[];
  float* m_lds = (float*)smem;                         // [64][260] = 66560 B
  char* uni = smem + 64*MSTRIDE*4;                     // 5632 B union
  float* lcw = (float*)uni;                            // [64][16]
  unsigned char* lidx  = (unsigned char*)(uni + 4096); // [64][16]
  unsigned char* lnear = (unsigned char*)(uni + 5120); // [64][8]
  short* A_st = (short*)uni;                           // [64][40] (phases 0-1 only)

  const int t = threadIdx.x;
  const int blk = blockIdx.x;                          // 2304
  const int b = blk / 576;
  const int p0 = (blk % 576) * 64;
  const float* xb = x + (size_t)b*CB*HW + p0;

  // ---- phase 0: load x row, BN+ReLU, split to bf16 hi/lo, stage A ----
  #pragma unroll
  for (int r = 0; r < 4; ++r) {
    int e = r*256 + t;
    int o = e >> 6, pl = e & 63;
    float vx = xb[(size_t)o*HW + pl];
    float f = fmaxf(0.f, fmaf(vx, st32[o], st32[CB+o]));
    unsigned short hb = bf16_rne(f);
    float res = f - bf16_tof(hb);
    unsigned short lb = bf16_rne(res);
    A_st[pl*40 + o]      = (short)hb;
    A_st[pl*40 + 16 + o] = (short)lb;
  }
  __syncthreads();

  const int w = t >> 6, l = t & 63;

  // ---- phase 1: MFMA, m tile -> LDS ----
  {
    const int prow = w*16 + (l & 15);
    const int k0 = (l >> 4) * 8;
    bf16x8 a = *(const bf16x8*)&A_st[prow*40 + k0];
    const int rowo = w*16 + (l >> 4)*4;
    const int coln = l & 15;
    #pragma unroll
    for (int ct = 0; ct < 16; ++ct) {
      bf16x8 b1 = *(const bf16x8*)&bfrag[(size_t)(ct*64 + l)*8];
      bf16x8 b2 = *(const bf16x8*)&bfrag[(size_t)((16 + ct)*64 + l)*8];
      f32x4 acc = {0.f, 0.f, 0.f, 0.f};
      acc = __builtin_amdgcn_mfma_f32_16x16x32_bf16(a, b1, acc, 0, 0, 0);
      acc = __builtin_amdgcn_mfma_f32_16x16x32_bf16(a, b2, acc, 0, 0, 0);
      #pragma unroll
      for (int i = 0; i < 4; ++i)
        m_lds[(rowo + i)*MSTRIDE + ct*16 + coln] = acc[i];
    }
  }
  __syncthreads();   // protects uni reuse (A_st -> lcw/lidx/lnear)

  // ---- phase 2: selection; 4 lanes per pixel, 64 colors each ----
  const int p = t >> 2, q = t & 3;
  float mv[64];
  #pragma unroll
  for (int r = 0; r < 16; ++r) {
    f32x4 v4 = *(const f32x4*)&m_lds[p*MSTRIDE + q*64 + r*4];
    mv[r*4+0] = v4[0]; mv[r*4+1] = v4[1]; mv[r*4+2] = v4[2]; mv[r*4+3] = v4[3];
  }

  float T[16], tmp[16];
  #pragma unroll
  for (int i = 0; i < 16; ++i) tmp[i] = mv[i];
  bitonic16<false>(tmp);
  #pragma unroll
  for (int i = 0; i < 16; ++i) T[i] = tmp[i];
  #pragma unroll
  for (int c = 1; c < 4; ++c) {
    #pragma unroll
    for (int i = 0; i < 16; ++i) tmp[i] = mv[c*16 + i];
    bitonic16<true>(tmp);
    #pragma unroll
    for (int i = 0; i < 16; ++i) T[i] = fmaxf(T[i], tmp[i]);
    bmerge16_desc(T);
  }
  // cross-lane merges among the 4 lanes of this pixel
  {
    float R[16];
    #pragma unroll
    for (int i = 0; i < 16; ++i) R[i] = fmaxf(T[i], __shfl_xor(T[15-i], 1));
    bmerge16_desc(R);
    #pragma unroll
    for (int i = 0; i < 16; ++i) T[i] = R[i];
    #pragma unroll
    for (int i = 0; i < 16; ++i) R[i] = fmaxf(T[i], __shfl_xor(T[15-i], 2));
    bmerge16_desc(R);
    #pragma unroll
    for (int i = 0; i < 16; ++i) T[i] = R[i];
  }
  const float tau = T[15], top = T[0];
  float Z = 0.f;
  #pragma unroll
  for (int i = 0; i < 16; ++i) Z += __expf(T[i] - top);
  const float iZ = 1.f / Z;

  // ---- phase 3a: per-lane counts + 4-lane prefix ----
  int cs = 0, cn = 0, cns = 0;
  #pragma unroll
  for (int j = 0; j < 64; ++j) {
    float v = mv[j];
    bool s = (v >= tau);
    bool nr = (fabsf(v - tau) <= DELTA);
    cs += s ? 1 : 0; cn += nr ? 1 : 0; cns += (s && nr) ? 1 : 0;
  }
  const int lb_ = l & ~3;
  int c0 = __shfl(cs, lb_), c1 = __shfl(cs, lb_+1), c2 = __shfl(cs, lb_+2), c3 = __shfl(cs, lb_+3);
  int n0 = __shfl(cn, lb_), n1 = __shfl(cn, lb_+1), n2 = __shfl(cn, lb_+2), n3 = __shfl(cn, lb_+3);
  int s0 = __shfl(cns, lb_), s1 = __shfl(cns, lb_+1), s2 = __shfl(cns, lb_+2), s3 = __shfl(cns, lb_+3);
  int offs = (q > 0 ? c0 : 0) + (q > 1 ? c1 : 0) + (q > 2 ? c2 : 0);
  int offn = (q > 0 ? n0 : 0) + (q > 1 ? n1 : 0) + (q > 2 ? n2 : 0);
  const int selN = c0 + c1 + c2 + c3;
  const int nearN = n0 + n1 + n2 + n3;
  const int nselN = s0 + s1 + s2 + s3;

  // ---- phase 3b: dense write + compact/near lists ----
  float* mspb = msp + (size_t)b*NCH*HW + p0;
  int isel = 0, inear = 0;
  #pragma unroll
  for (int j = 0; j < 64; ++j) {
    const int k = q*64 + j;
    float v = mv[j];
    bool s = (v >= tau);
    bool nr = (fabsf(v - tau) <= DELTA);
    float wv = s ? __expf(v - top) * iZ : 0.f;
    mspb[(size_t)k*HW + p] = wv;
    if (s) {
      int slot = offs + isel;
      if (slot < 16) { lcw[p*16 + slot] = wv; lidx[p*16 + slot] = (unsigned char)k; }
      ++isel;
    }
    if (nr) {
      int gs = offn + inear;
      if (gs < 8) lnear[p*8 + gs] = (unsigned char)k;
      ++inear;
    }
  }

  // ---- phase 3c: epilogue (one lane per pixel) ----
  if (q == 0)
    k2_epilogue(b, p0 + p, p, selN, nearN, nselN, lcw, lidx, lnear,
                cidx, cw, flagcnt, entries);
}

// ---------------- K2b: fixup for near-boundary pixels ------------------------

__global__ __launch_bounds__(64) void k2b_fix(
    const float* __restrict__ bfeat, const float* __restrict__ wb,
    const float* __restrict__ bb, const float* __restrict__ wmg,
    const double* __restrict__ st64,
    const unsigned* __restrict__ flagcnt, const FlagEntry* __restrict__ entries,
    float* __restrict__ msp, unsigned* __restrict__ cidx, float* __restrict__ cw)
{
  const unsigned n = *flagcnt;
  const unsigned i = blockIdx.x*64u + threadIdx.x;
  if (i >= n) return;
  FlagEntry e = entries[i];
  const int b = (int)(e.pix / HW), p = (int)(e.pix % HW);

  const float* bfb = bfeat + (size_t)b*CIN*HW;
  float vals[CIN];
  #pragma unroll
  for (int c = 0; c < CIN; ++c) vals[c] = bfb[(size_t)c*HW + p];

  double xx[CB];
  #pragma unroll
  for (int o = 0; o < CB; ++o) xx[o] = (double)bb[o];
  #pragma unroll 4
  for (int c = 0; c < CIN; ++c) {
    const double v = (double)vals[c];
    #pragma unroll
    for (int o = 0; o < CB; ++o) xx[o] = fma(v, (double)wb[o*CIN + c], xx[o]);
  }
  double ft[CB];
  #pragma unroll
  for (int o = 0; o < CB; ++o) ft[o] = fmax(0.0, xx[o]*st64[o] + st64[CB+o]);

  float* mb = msp + (size_t)b*NCH*HW;
  unsigned char* cb_ = (unsigned char*)cidx + (size_t)e.pix*16;
  float* cwp = cw + (size_t)e.pix*16;

  if (e.r0) {
    double tv[16]; int ti[16];
    #pragma unroll
    for (int j = 0; j < 16; ++j) { tv[j] = -1.0e300; ti[j] = 1 << 20; }
    for (int k = 0; k < NCH; ++k) {
      double m = 0.0;
      #pragma unroll
      for (int c = 0; c < CB; ++c) m = fma(ft[c], (double)wmg[k*CB + c], m);
      if (m > tv[15] || (m == tv[15] && k < ti[15])) {
        int pos = 15;
        while (pos > 0 && (m > tv[pos-1] || (m == tv[pos-1] && k < ti[pos-1]))) {
          tv[pos] = tv[pos-1]; ti[pos] = ti[pos-1]; --pos;
        }
        tv[pos] = m; ti[pos] = k;
      }
    }
    double top = tv[0], Z = 0.0, wv64[16];
    #pragma unroll
    for (int j = 0; j < 16; ++j) { wv64[j] = exp(tv[j] - top); Z += wv64[j]; }
    double iZ = 1.0 / Z;
    #pragma unroll
    for (int j = 0; j < 4; ++j) ((unsigned*)cb_)[j] = 0u;
    #pragma unroll
    for (int j = 0; j < 16; ++j) cwp[j] = 0.f;
    int oc = 0;
    for (int k = 0; k < NCH; ++k) {
      float w = 0.f;
      #pragma unroll
      for (int j = 0; j < 16; ++j) if (ti[j] == k) w = (float)(wv64[j] * iZ);
      mb[(size_t)k*HW + p] = w;
      if (w != 0.f && oc < 16) { cb_[oc] = (unsigned char)k; cwp[oc] = w; ++oc; }
    }
    return;
  }

  const int cnt = (e.cnt > 8) ? 8 : (int)e.cnt;
  int need = (int)e.need; if (need > cnt) need = cnt;

  unsigned char kOrig[16]; float wOrig[16];
  #pragma unroll
  for (int j = 0; j < 16; ++j) kOrig[j] = cb_[j];
  #pragma unroll
  for (int j = 0; j < 16; ++j) wOrig[j] = cwp[j];

  int kr[8]; double m64[8]; float wold[8];
  #pragma unroll
  for (int j = 0; j < 8; ++j) {
    kr[j] = (j < cnt) ? (int)e.ks[j] : 0;
    double a = 0.0;
    if (j < cnt) {
      #pragma unroll
      for (int c = 0; c < CB; ++c) a = fma(ft[c], (double)wmg[kr[j]*CB + c], a);
    }
    m64[j] = a;
    float w = 0.f;
    if (j < cnt) {
      #pragma unroll
      for (int qq = 0; qq < 16; ++qq)
        if ((int)kOrig[qq] == kr[j] && wOrig[qq] > 0.f) w = wOrig[qq];
    }
    wold[j] = w;
  }
  int rank[8];
  #pragma unroll
  for (int j = 0; j < 8; ++j) {
    int r = 0;
    #pragma unroll
    for (int j2 = 0; j2 < 8; ++j2) {
      if (j2 < cnt && j2 != j) {
        bool gt = (m64[j2] > m64[j]) || (m64[j2] == m64[j] && kr[j2] < kr[j]);
        r += gt ? 1 : 0;
      }
    }
    rank[j] = (j < cnt) ? r : 99;
  }
  float ws_[8]; int nw = 0;
  for (int j = 0; j < 8; ++j) if (j < cnt && wold[j] > 0.f) { ws_[nw] = wold[j]; ++nw; }
  for (int a2 = 1; a2 < nw; ++a2) {
    float v = ws_[a2]; int qq = a2;
    while (qq > 0 && ws_[qq-1] < v) { ws_[qq] = ws_[qq-1]; --qq; }
    ws_[qq] = v;
  }
  float wn[8];
  #pragma unroll
  for (int j = 0; j < 8; ++j) {
    float v = 0.f;
    if (j < cnt && rank[j] < need && rank[j] < nw) v = ws_[rank[j]];
    wn[j] = v;
    if (j < cnt) mb[(size_t)kr[j]*HW + p] = v;
  }

  unsigned char nk[16]; float nwv[16];
  int on = 0, ii = 0, jj = 0;
  while (ii < 16 || jj < cnt) {
    if (ii < 16 && wOrig[ii] <= 0.f) { ++ii; continue; }
    int ko = (ii < 16) ? (int)kOrig[ii] : (1 << 20);
    int kj = (jj < cnt) ? kr[jj] : (1 << 20);
    if (ko >= (1 << 20) && kj >= (1 << 20)) break;
    if (ko < kj) {
      if (on < 16) { nk[on] = (unsigned char)ko; nwv[on] = wOrig[ii]; ++on; }
      ++ii;
    } else if (kj < ko) {
      if (wn[jj] > 0.f && on < 16) { nk[on] = (unsigned char)kj; nwv[on] = wn[jj]; ++on; }
      ++jj;
    } else {
      if (wn[jj] > 0.f && on < 16) { nk[on] = (unsigned char)kj; nwv[on] = wn[jj]; ++on; }
      ++ii; ++jj;
    }
  }
  for (int j = on; j < 16; ++j) { nk[j] = 0; nwv[j] = 0.f; }
  #pragma unroll
  for (int qq = 0; qq < 4; ++qq) {
    unsigned pk = (unsigned)nk[qq*4] | ((unsigned)nk[qq*4+1] << 8)
                | ((unsigned)nk[qq*4+2] << 16) | ((unsigned)nk[qq*4+3] << 24);
    ((unsigned*)cb_)[qq] = pk;
  }
  #pragma unroll
  for (int j = 0; j < 16; ++j) cwp[j] = nwv[j];
}

// ---------------- K3: num/den accumulation -----------------------------------

__global__ __launch_bounds__(256) void k3_accum(
    const uint4* __restrict__ cidx, const float4* __restrict__ cw4,
    const float* __restrict__ img, float* __restrict__ part)
{
  __shared__ float acc[1024];
  const int t = threadIdx.x, blk = blockIdx.x;
  for (int i = t; i < 1024; i += 256) acc[i] = 0.f;
  __syncthreads();
  const int b = blk / 144;
  const int p = (blk % 144) * 256 + t;
  const float* imb = img + (size_t)b*3*HW;
  const int g = b*HW + p;
  uint4 iv = cidx[g];
  unsigned ivq[4] = {iv.x, iv.y, iv.z, iv.w};
  float r = imb[p], g_ = imb[HW + p], bl = imb[2*HW + p];
  #pragma unroll
  for (int q = 0; q < 4; ++q) {
    float4 wv = cw4[(size_t)g*4 + q];
    float wvv[4] = {wv.x, wv.y, wv.z, wv.w};
    #pragma unroll
    for (int u = 0; u < 4; ++u) {
      int k = (int)((ivq[q] >> (8*u)) & 255u);
      float wgt = wvv[u];
      atomicAdd(&acc[k],       wgt * r);
      atomicAdd(&acc[256 + k], wgt * g_);
      atomicAdd(&acc[512 + k], wgt * bl);
      atomicAdd(&acc[768 + k], wgt);
    }
  }
  __syncthreads();
  for (int i = t; i < 1024; i += 256) part[(size_t)blk*1024 + i] = acc[i];
}

// ---------------- K4: palette ------------------------------------------------

__global__ __launch_bounds__(256) void k4_pal(
    const float* __restrict__ part, float* __restrict__ out_pal)
{
  __shared__ float acc[1024];
  const int b = blockIdx.x, t = threadIdx.x;
  for (int s = t; s < 1024; s += 256) {
    float a = 0.f;
    for (int i = 0; i < 144; ++i) a += part[(size_t)(b*144 + i)*1024 + s];
    acc[s] = a;
  }
  __syncthreads();
  for (int s = t; s < 768; s += 256) {
    int k = s & 255;
    float den = acc[768 + k] + 1e-8f;
    out_pal[(size_t)b*768 + s] = acc[s] / den;
  }
}

// ---------------- K5: recolored image ----------------------------------------

__global__ __launch_bounds__(256) void k5_img(
    const uint4* __restrict__ cidx, const float4* __restrict__ cw4,
    const float* __restrict__ pal, float* __restrict__ outimg)
{
  __shared__ float lp[768];
  const int t = threadIdx.x, blk = blockIdx.x;
  const int b = blk / 144;
  for (int i = t; i < 768; i += 256) lp[i] = pal[(size_t)b*768 + i];
  __syncthreads();
  const int p = (blk % 144) * 256 + t;
  const int g = b*HW + p;
  uint4 iv = cidx[g];
  unsigned ivq[4] = {iv.x, iv.y, iv.z, iv.w};
  float r = 0.f, g_ = 0.f, bl = 0.f;
  #pragma unroll
  for (int q = 0; q < 4; ++q) {
    float4 wv = cw4[(size_t)g*4 + q];
    float wvv[4] = {wv.x, wv.y, wv.z, wv.w};
    #pragma unroll
    for (int u = 0; u < 4; ++u) {
      int k = (int)((ivq[q] >> (8*u)) & 255u);
      float wgt = wvv[u];
      r  = fmaf(wgt, lp[k],       r);
      g_ = fmaf(wgt, lp[256 + k], g_);
      bl = fmaf(wgt, lp[512 + k], bl);
    }
  }
  float* ob = outimg + (size_t)b*3*HW;
  ob[p] = r; ob[HW + p] = g_; ob[2*HW + p] = bl;
}

// ---------------- launcher ---------------------------------------------------

extern "C" void kernel_launch(void* const* d_in, const int* in_sizes, int n_in,
                              void* d_out, int out_size, void* d_ws, size_t ws_size,
                              hipStream_t stream)
{
  const float* img   = (const float*)d_in[0];
  const float* bfeat = (const float*)d_in[1];
  const float* wb    = (const float*)d_in[2];
  const float* bb    = (const float*)d_in[3];
  const float* gam   = (const float*)d_in[4];
  const float* bet   = (const float*)d_in[5];
  const float* wm    = (const float*)d_in[6];

  float* out_img = (float*)d_out;                 // [4,3,192,192]
  float* out_msp = (float*)d_out + 442368;        // [4,256,192,192]
  float* out_pal = (float*)d_out + 38191104;      // [4,3,256,1,1]

  char* w = (char*)d_ws;
  float*     ws_x       = (float*)(w);                     // 9,437,184 B (dead after k2 -> reused for k3 partials)
  double*    ws_part    = (double*)(w + 9437184);          //   147,456 B
  double*    ws_st64    = (double*)(w + 9584640);          //       256 B
  float*     ws_st32    = (float*)(w + 9584896);           //       128 B
  unsigned*  ws_flagcnt = (unsigned*)(w + 9585152);        //       256 B pad
  FlagEntry* ws_entries = (FlagEntry*)(w + 9585408);       // 2,359,296 B
  unsigned*  ws_cidx    = (unsigned*)(w + 11944704);       // 2,359,296 B
  float*     ws_cw      = (float*)(w + 14304000);          // 9,437,184 B
  float*     ws_nd      = ws_x;                            // aliases ws_x (x dead after k2)
  short*     ws_bfrag   = (short*)(w + 23741184);          //    32,768 B

  k0_zero<<<dim3(1), dim3(1), 0, stream>>>(ws_flagcnt);
  k1_conv<<<dim3(576), dim3(256), 0, stream>>>(bfeat, wb, bb, ws_x, ws_part);
  k1b_stats<<<dim3(1), dim3(64), 0, stream>>>(ws_part, gam, bet, ws_st64, ws_st32);
  k1c_bfrag<<<dim3(1), dim3(256), 0, stream>>>(wm, ws_bfrag);
  k2_main<<<dim3(2304), dim3(256), 72192, stream>>>(ws_x, ws_bfrag, ws_st32, out_msp,
                                                    ws_cidx, ws_cw, ws_flagcnt, ws_entries);
  k2b_fix<<<dim3(2304), dim3(64), 0, stream>>>(bfeat, wb, bb, wm, ws_st64,
                                               ws_flagcnt, ws_entries, out_msp, ws_cidx, ws_cw);
  k3_accum<<<dim3(576), dim3(256), 0, stream>>>((const uint4*)ws_cidx, (const float4*)ws_cw,
                                                img, ws_nd);
  k4_pal<<<dim3(4), dim3(256), 0, stream>>>(ws_nd, out_pal);
  k5_img<<<dim3(576), dim3(256), 0, stream>>>((const uint4*)ws_cidx, (const float4*)ws_cw,
                                              out_pal, out_img);
}

// Round 6
// 295.924 us; speedup vs baseline: 2.4869x; 1.2857x over previous
//
#include <hip/hip_runtime.h>

#define HW    36864
#define NB    4
#define NCH   256
#define CIN   64
#define CB    16
#define NPIX  (NB*HW)          // 147456
#define DELTA 1e-4f

typedef short bf16x8 __attribute__((ext_vector_type(8)));
typedef float f32x4  __attribute__((ext_vector_type(4)));

struct FlagEntry {
  unsigned pix;
  unsigned char cnt, need, r0, r1;   // r0 = full-f64-redo flag
  unsigned char ks[8];
};                              // 16 B

// ---------------- bf16 split helpers (RNE) -----------------------------------

__device__ __forceinline__ unsigned short bf16_rne(float x) {
  unsigned u = __float_as_uint(x);
  unsigned r = u + 0x7fffu + ((u >> 16) & 1u);
  return (unsigned short)(r >> 16);
}
__device__ __forceinline__ float bf16_tof(unsigned short h) {
  return __uint_as_float(((unsigned)h) << 16);
}

// ---------------- sorting networks (values only, fully unrolled) -------------

template<bool ASC>
__device__ __forceinline__ void bitonic16(float* v) {
  #pragma unroll
  for (int K = 2; K <= 16; K <<= 1) {
    #pragma unroll
    for (int J = K >> 1; J > 0; J >>= 1) {
      #pragma unroll
      for (int i = 0; i < 16; ++i) {
        int l = i ^ J;
        if (l > i) {
          bool up = (((i & K) == 0) == ASC);
          float a = v[i], b = v[l];
          float lo = fminf(a, b), hi = fmaxf(a, b);
          v[i] = up ? lo : hi;
          v[l] = up ? hi : lo;
        }
      }
    }
  }
}

__device__ __forceinline__ void bmerge16_desc(float* v) {
  #pragma unroll
  for (int J = 8; J > 0; J >>= 1) {
    #pragma unroll
    for (int i = 0; i < 16; ++i) {
      int l = i ^ J;
      if (l > i) {
        float a = v[i], b = v[l];
        float lo = fminf(a, b), hi = fmaxf(a, b);
        v[i] = hi; v[l] = lo;
      }
    }
  }
}

// ---------------- K0: zero flag counter --------------------------------------

__global__ void k0_zero(unsigned* flagcnt) { *flagcnt = 0u; }

// ---------------- K1: 1x1 conv (64->16) + f64 stats partials -----------------

__global__ __launch_bounds__(256) void k1_conv(
    const float* __restrict__ bfeat, const float* __restrict__ wb,
    const float* __restrict__ bb, float* __restrict__ xout,
    double* __restrict__ part)
{
  __shared__ float wbT[CIN][CB];          // 4 KB
  __shared__ double redS[4][CB];
  __shared__ double redQ[4][CB];
  const int t = threadIdx.x;
  for (int i = t; i < CIN*CB; i += 256) {
    int o = i >> 6, c = i & 63;
    wbT[c][o] = wb[i];
  }
  __syncthreads();

  const int blk = blockIdx.x;             // 576
  const int b = blk / 144, seg = blk % 144;
  const int p = seg * 256 + t;
  const float* bfb = bfeat + (size_t)b * CIN * HW;

  float acc[CB];
  #pragma unroll
  for (int o = 0; o < CB; ++o) acc[o] = bb[o];

  for (int c = 0; c < CIN; ++c) {
    float v = bfb[(size_t)c*HW + p];
    #pragma unroll
    for (int o4 = 0; o4 < 4; ++o4) {
      float4 w4 = *(const float4*)&wbT[c][o4*4];
      acc[o4*4+0] = fmaf(v, w4.x, acc[o4*4+0]);
      acc[o4*4+1] = fmaf(v, w4.y, acc[o4*4+1]);
      acc[o4*4+2] = fmaf(v, w4.z, acc[o4*4+2]);
      acc[o4*4+3] = fmaf(v, w4.w, acc[o4*4+3]);
    }
  }

  float* xb = xout + (size_t)b * CB * HW;
  #pragma unroll
  for (int o = 0; o < CB; ++o) xb[(size_t)o*HW + p] = acc[o];

  const int wv = t >> 6, lane = t & 63;
  #pragma unroll
  for (int o = 0; o < CB; ++o) {
    double a = (double)acc[o], q = a*a;
    for (int off = 32; off; off >>= 1) { a += __shfl_xor(a, off); q += __shfl_xor(q, off); }
    if (lane == 0) { redS[wv][o] = a; redQ[wv][o] = q; }
  }
  __syncthreads();
  if (t < CB) {
    double a = redS[0][t] + redS[1][t] + redS[2][t] + redS[3][t];
    part[(size_t)blk*32 + t] = a;
  } else if (t < 32) {
    int o = t - CB;
    double q = redQ[0][o] + redQ[1][o] + redQ[2][o] + redQ[3][o];
    part[(size_t)blk*32 + t] = q;
  }
}

// ---------------- K1b: finalize BN stats -------------------------------------

__global__ __launch_bounds__(64) void k1b_stats(
    const double* __restrict__ part, const float* __restrict__ gam,
    const float* __restrict__ bet, double* __restrict__ st64, float* __restrict__ st32)
{
  __shared__ double sh[32];
  const int t = threadIdx.x;
  if (t < 32) {
    double a = 0.0;
    #pragma unroll 8
    for (int i = 0; i < 576; ++i) a += part[(size_t)i*32 + t];
    sh[t] = a;
  }
  __syncthreads();
  if (t < CB) {
    const double N = (double)NPIX;
    double mean = sh[t] / N;
    double var  = sh[16+t] / N - mean*mean;
    double rstd = 1.0 / sqrt(var + 1e-5);
    double scl = (double)gam[t] * rstd;
    double sft = (double)bet[t] - mean*scl;
    st64[t] = scl; st64[CB+t] = sft;
    st32[t] = (float)scl; st32[CB+t] = (float)sft;
  }
}

// ---------------- K1c: build split-bf16 B fragments for MFMA -----------------

__global__ __launch_bounds__(256) void k1c_bfrag(
    const float* __restrict__ wm, short* __restrict__ bfrag)
{
  const int t = threadIdx.x;
  for (int e = t; e < 2048; e += 256) {       // (v, ct, lane)
    const int v = e >> 10, ct = (e >> 6) & 15, l = e & 63;
    const int n = l & 15, g = l >> 4;
    const int col = ct*16 + n;
    short out[8];
    #pragma unroll
    for (int j = 0; j < 8; ++j) {
      const int k = g*8 + j;
      const int kk = k & 15;
      const bool hi_half = (k < 16);
      float w = wm[col*CB + kk];
      unsigned short hb = bf16_rne(w);
      float res = w - bf16_tof(hb);
      unsigned short lb = bf16_rne(res);
      bool use_hi = ((v == 0) == hi_half);
      out[j] = (short)(use_hi ? hb : lb);
    }
    bf16x8 pk;
    #pragma unroll
    for (int j = 0; j < 8; ++j) pk[j] = out[j];
    *(bf16x8*)&bfrag[(size_t)e * 8] = pk;
  }
}

// ---------------- K2: main per-pixel kernel (MFMA + LDS m-tile) --------------

__device__ __forceinline__ void k2_epilogue(int b, int p, int pxl,
    int selN, int nearN, int nselN,
    float* lcw, unsigned char* lidx, unsigned char* lnear,
    unsigned* cidx, float* cw, unsigned* flagcnt, FlagEntry* entries)
{
  int start = selN < 16 ? selN : 16;
  for (int j = start; j < 16; ++j) { lcw[pxl*16 + j] = 0.f; lidx[pxl*16 + j] = 0; }
  unsigned g = (unsigned)(b*HW + p);
  uint4 iv = *(uint4*)&lidx[pxl*16];
  ((uint4*)cidx)[g] = iv;
  float4* cwq = (float4*)cw;
  #pragma unroll
  for (int q = 0; q < 4; ++q) cwq[(size_t)g*4 + q] = *(float4*)&lcw[pxl*16 + q*4];
  bool flag = (nearN > 1) || (selN != 16);
  if (flag) {
    unsigned slot = atomicAdd(flagcnt, 1u);
    FlagEntry e;
    e.pix = g;
    int cnt = nearN < 8 ? nearN : 8;
    e.cnt = (unsigned char)cnt;
    int nsure = selN - nselN;
    int need = 16 - nsure;
    if (need < 0) need = 0;
    if (need > cnt) need = cnt;
    e.need = (unsigned char)need;
    e.r0 = (nearN > 8 || selN != 16) ? 1 : 0;
    e.r1 = 0;
    #pragma unroll
    for (int j = 0; j < 8; ++j) e.ks[j] = (j < cnt) ? lnear[pxl*8 + j] : 0;
    entries[slot] = e;
  }
}

#define MSTRIDE 260

__global__ __launch_bounds__(256, 2) void k2_main(
    const float* __restrict__ x, const short* __restrict__ bfrag,
    const float* __restrict__ st32, float* __restrict__ msp,
    unsigned* __restrict__ cidx, float* __restrict__ cw,
    unsigned* __restrict__ flagcnt, FlagEntry* __restrict__ entries)
{
  extern __shared__ char smem[];
  float* m_lds = (float*)smem;                         // [64][260] = 66560 B
  char* uni = smem + 64*MSTRIDE*4;                     // 5632 B union
  float* lcw = (float*)uni;                            // [64][16]
  unsigned char* lidx  = (unsigned char*)(uni + 4096); // [64][16]
  unsigned char* lnear = (unsigned char*)(uni + 5120); // [64][8]
  short* A_st = (short*)uni;                           // [64][40] (phases 0-1 only)

  const int t = threadIdx.x;
  const int blk = blockIdx.x;                          // 2304
  const int b = blk / 576;
  const int p0 = (blk % 576) * 64;
  const float* xb = x + (size_t)b*CB*HW + p0;

  // ---- phase 0: load x row, BN+ReLU, split to bf16 hi/lo, stage A ----
  #pragma unroll
  for (int r = 0; r < 4; ++r) {
    int e = r*256 + t;
    int o = e >> 6, pl = e & 63;
    float vx = xb[(size_t)o*HW + pl];
    float f = fmaxf(0.f, fmaf(vx, st32[o], st32[CB+o]));
    unsigned short hb = bf16_rne(f);
    float res = f - bf16_tof(hb);
    unsigned short lb = bf16_rne(res);
    A_st[pl*40 + o]      = (short)hb;
    A_st[pl*40 + 16 + o] = (short)lb;
  }
  __syncthreads();

  const int w = t >> 6, l = t & 63;

  // ---- phase 1: MFMA, m tile -> LDS ----
  {
    const int prow = w*16 + (l & 15);
    const int k0 = (l >> 4) * 8;
    bf16x8 a = *(const bf16x8*)&A_st[prow*40 + k0];
    const int rowo = w*16 + (l >> 4)*4;
    const int coln = l & 15;
    #pragma unroll
    for (int ct = 0; ct < 16; ++ct) {
      bf16x8 b1 = *(const bf16x8*)&bfrag[(size_t)(ct*64 + l)*8];
      bf16x8 b2 = *(const bf16x8*)&bfrag[(size_t)((16 + ct)*64 + l)*8];
      f32x4 acc = {0.f, 0.f, 0.f, 0.f};
      acc = __builtin_amdgcn_mfma_f32_16x16x32_bf16(a, b1, acc, 0, 0, 0);
      acc = __builtin_amdgcn_mfma_f32_16x16x32_bf16(a, b2, acc, 0, 0, 0);
      #pragma unroll
      for (int i = 0; i < 4; ++i)
        m_lds[(rowo + i)*MSTRIDE + ct*16 + coln] = acc[i];
    }
  }
  __syncthreads();   // protects uni reuse (A_st -> lcw/lidx/lnear)

  // ---- phase 2: selection; 4 lanes per pixel, 64 colors each ----
  const int p = t >> 2, q = t & 3;
  float mv[64];
  #pragma unroll
  for (int r = 0; r < 16; ++r) {
    f32x4 v4 = *(const f32x4*)&m_lds[p*MSTRIDE + q*64 + r*4];
    mv[r*4+0] = v4[0]; mv[r*4+1] = v4[1]; mv[r*4+2] = v4[2]; mv[r*4+3] = v4[3];
  }

  float T[16], tmp[16];
  #pragma unroll
  for (int i = 0; i < 16; ++i) tmp[i] = mv[i];
  bitonic16<false>(tmp);
  #pragma unroll
  for (int i = 0; i < 16; ++i) T[i] = tmp[i];
  #pragma unroll
  for (int c = 1; c < 4; ++c) {
    #pragma unroll
    for (int i = 0; i < 16; ++i) tmp[i] = mv[c*16 + i];
    bitonic16<true>(tmp);
    #pragma unroll
    for (int i = 0; i < 16; ++i) T[i] = fmaxf(T[i], tmp[i]);
    bmerge16_desc(T);
  }
  // cross-lane merges among the 4 lanes of this pixel
  {
    float R[16];
    #pragma unroll
    for (int i = 0; i < 16; ++i) R[i] = fmaxf(T[i], __shfl_xor(T[15-i], 1));
    bmerge16_desc(R);
    #pragma unroll
    for (int i = 0; i < 16; ++i) T[i] = R[i];
    #pragma unroll
    for (int i = 0; i < 16; ++i) R[i] = fmaxf(T[i], __shfl_xor(T[15-i], 2));
    bmerge16_desc(R);
    #pragma unroll
    for (int i = 0; i < 16; ++i) T[i] = R[i];
  }
  const float tau = T[15], top = T[0];
  float Z = 0.f;
  #pragma unroll
  for (int i = 0; i < 16; ++i) Z += __expf(T[i] - top);
  const float iZ = 1.f / Z;

  // ---- phase 3a: per-lane counts + 4-lane prefix ----
  int cs = 0, cn = 0, cns = 0;
  #pragma unroll
  for (int j = 0; j < 64; ++j) {
    float v = mv[j];
    bool s = (v >= tau);
    bool nr = (fabsf(v - tau) <= DELTA);
    cs += s ? 1 : 0; cn += nr ? 1 : 0; cns += (s && nr) ? 1 : 0;
  }
  const int lb_ = l & ~3;
  int c0 = __shfl(cs, lb_), c1 = __shfl(cs, lb_+1), c2 = __shfl(cs, lb_+2), c3 = __shfl(cs, lb_+3);
  int n0 = __shfl(cn, lb_), n1 = __shfl(cn, lb_+1), n2 = __shfl(cn, lb_+2), n3 = __shfl(cn, lb_+3);
  int s0 = __shfl(cns, lb_), s1 = __shfl(cns, lb_+1), s2 = __shfl(cns, lb_+2), s3 = __shfl(cns, lb_+3);
  int offs = (q > 0 ? c0 : 0) + (q > 1 ? c1 : 0) + (q > 2 ? c2 : 0);
  int offn = (q > 0 ? n0 : 0) + (q > 1 ? n1 : 0) + (q > 2 ? n2 : 0);
  const int selN = c0 + c1 + c2 + c3;
  const int nearN = n0 + n1 + n2 + n3;
  const int nselN = s0 + s1 + s2 + s3;

  // ---- phase 3b: dense write + compact/near lists ----
  float* mspb = msp + (size_t)b*NCH*HW + p0;
  int isel = 0, inear = 0;
  #pragma unroll
  for (int j = 0; j < 64; ++j) {
    const int k = q*64 + j;
    float v = mv[j];
    bool s = (v >= tau);
    bool nr = (fabsf(v - tau) <= DELTA);
    float wv = s ? __expf(v - top) * iZ : 0.f;
    mspb[(size_t)k*HW + p] = wv;
    if (s) {
      int slot = offs + isel;
      if (slot < 16) { lcw[p*16 + slot] = wv; lidx[p*16 + slot] = (unsigned char)k; }
      ++isel;
    }
    if (nr) {
      int gs = offn + inear;
      if (gs < 8) lnear[p*8 + gs] = (unsigned char)k;
      ++inear;
    }
  }

  // ---- phase 3c: epilogue (one lane per pixel) ----
  if (q == 0)
    k2_epilogue(b, p0 + p, p, selN, nearN, nselN, lcw, lidx, lnear,
                cidx, cw, flagcnt, entries);
}

// ---------------- K2b: wave-cooperative fixup for near-boundary pixels -------
// One 64-lane wave per flagged pixel; grid-stride over entries.

__global__ __launch_bounds__(64) void k2b_fix(
    const float* __restrict__ bfeat, const float* __restrict__ wb,
    const float* __restrict__ bb, const float* __restrict__ wmg,
    const double* __restrict__ st64,
    const unsigned* __restrict__ flagcnt, const FlagEntry* __restrict__ entries,
    float* __restrict__ msp, unsigned* __restrict__ cidx, float* __restrict__ cw)
{
  __shared__ float wbT[CB][CIN];     // 4 KB: wbT[o][c] = wb[o*CIN+c]
  __shared__ float  wOrigL[16];
  __shared__ int    kOrigL[16];
  __shared__ float  wnL[8];
  __shared__ int    kL[8];
  __shared__ double tvL[16];
  __shared__ int    tiL[16];
  __shared__ float  wvL[16];

  const int lane = threadIdx.x;
  for (int i = lane; i < CB*CIN; i += 64) wbT[i >> 6][i & 63] = wb[i];
  __syncthreads();

  const unsigned n = *flagcnt;
  for (unsigned idx = blockIdx.x; idx < n; idx += gridDim.x) {
    FlagEntry e = entries[idx];
    const int b = (int)(e.pix / HW), p = (int)(e.pix % HW);

    // ---- f64 conv (wave-parallel over channels) + BN + ReLU ----
    const double v = (double)bfeat[(size_t)b*CIN*HW + (size_t)lane*HW + p];
    double ft[CB];
    #pragma unroll
    for (int o = 0; o < CB; ++o) {
      double s = v * (double)wbT[o][lane];
      #pragma unroll
      for (int off = 32; off; off >>= 1) s += __shfl_xor(s, off);
      s += (double)bb[o];                       // all lanes hold same value
      ft[o] = fmax(0.0, s*st64[o] + st64[CB+o]);
    }

    float* mb = msp + (size_t)b*NCH*HW;
    unsigned char* cb_ = (unsigned char*)cidx + (size_t)e.pix*16;
    float* cwp = cw + (size_t)e.pix*16;

    if (e.r0) {
      // ---- full f64 redo: wave-parallel top-16, (value desc, index asc) ----
      double mm[4]; int kk4[4];
      #pragma unroll
      for (int u = 0; u < 4; ++u) {
        const int k = lane + 64*u; kk4[u] = k;
        const float* wr = wmg + k*CB;
        double a = 0.0;
        #pragma unroll
        for (int c = 0; c < CB; ++c) a = fma(ft[c], (double)wr[c], a);
        mm[u] = a;
      }
      for (int j = 0; j < 16; ++j) {
        double bm = mm[0]; int bk = kk4[0];
        #pragma unroll
        for (int u = 1; u < 4; ++u) {
          bool gt = (mm[u] > bm) || (mm[u] == bm && kk4[u] < bk);
          if (gt) { bm = mm[u]; bk = kk4[u]; }
        }
        #pragma unroll
        for (int off = 32; off; off >>= 1) {
          double om = __shfl_xor(bm, off);
          int ok = __shfl_xor(bk, off);
          bool gt = (om > bm) || (om == bm && ok < bk);
          if (gt) { bm = om; bk = ok; }
        }
        if (lane == 0) { tvL[j] = bm; tiL[j] = bk; }
        #pragma unroll
        for (int u = 0; u < 4; ++u) if (kk4[u] == bk) mm[u] = -1.0e300;
      }
      __syncthreads();
      const double top = tvL[0];
      double ej = (lane < 16) ? exp(tvL[lane] - top) : 0.0;
      double Z = ej;
      #pragma unroll
      for (int off = 32; off; off >>= 1) Z += __shfl_xor(Z, off);
      if (lane < 16) wvL[lane] = (float)(ej / Z);
      __syncthreads();
      int tiR[16]; float wvR[16];
      #pragma unroll
      for (int j = 0; j < 16; ++j) { tiR[j] = tiL[j]; wvR[j] = wvL[j]; }
      // dense write: 4 colors per lane
      #pragma unroll
      for (int u = 0; u < 4; ++u) {
        const int k = lane + 64*u;
        float wv = 0.f;
        #pragma unroll
        for (int j = 0; j < 16; ++j) if (tiR[j] == k) wv = wvR[j];
        mb[(size_t)k*HW + p] = wv;
      }
      // compact rebuild (ascending k, skip zero weights)
      if (lane == 0) {
        unsigned used = 0; int on = 0;
        for (int it = 0; it < 16; ++it) {
          int bk = 1 << 20;
          #pragma unroll
          for (int j = 0; j < 16; ++j)
            if (!((used >> j) & 1u) && tiR[j] < bk) bk = tiR[j];
          if (bk >= (1 << 20)) break;
          float bw = 0.f;
          #pragma unroll
          for (int j = 0; j < 16; ++j)
            if (tiR[j] == bk) { bw = wvR[j]; used |= (1u << j); }
          if (bw != 0.f && on < 16) { cb_[on] = (unsigned char)bk; cwp[on] = bw; ++on; }
        }
        for (int j = on; j < 16; ++j) { cb_[j] = 0; cwp[j] = 0.f; }
      }
      __syncthreads();
      continue;
    }

    // ---- light path (selN==16 guaranteed; lane-parallel over near colors) ----
    const int cnt = (e.cnt > 8) ? 8 : (int)e.cnt;
    int need = (int)e.need; if (need > cnt) need = cnt;

    if (lane < 16) { wOrigL[lane] = cwp[lane]; kOrigL[lane] = (int)cb_[lane]; }
    __syncthreads();

    const int myk = (lane < cnt) ? (int)e.ks[lane] : 0x7fffffff;
    double mj = 0.0;
    if (lane < cnt) {
      const float* wr = wmg + myk*CB;
      #pragma unroll
      for (int c = 0; c < CB; ++c) mj = fma(ft[c], (double)wr[c], mj);
    }
    float woldj = 0.f;
    if (lane < cnt) {
      #pragma unroll
      for (int q = 0; q < 16; ++q) {
        if (kOrigL[q] == myk && wOrigL[q] > 0.f) woldj = wOrigL[q];
      }
    }
    // rank among the cnt near colors: (m desc, k asc)
    int rankj = 0;
    #pragma unroll
    for (int j2 = 0; j2 < 8; ++j2) {
      double m2 = __shfl(mj, j2);
      int k2v = __shfl(myk, j2);
      if (lane < cnt && j2 < cnt && j2 != lane) {
        bool gt = (m2 > mj) || (m2 == mj && k2v < myk);
        rankj += gt ? 1 : 0;
      }
    }
    // gather all wold; count positives
    float w2[8];
    #pragma unroll
    for (int j2 = 0; j2 < 8; ++j2) w2[j2] = __shfl(woldj, j2);
    int nw = 0;
    #pragma unroll
    for (int j2 = 0; j2 < 8; ++j2) if (j2 < cnt && w2[j2] > 0.f) ++nw;
    // rank-th largest positive wold (equal values interchangeable)
    float wnj = 0.f;
    if (lane < cnt && rankj < need && rankj < nw) {
      #pragma unroll
      for (int cand = 0; cand < 8; ++cand) {
        if (cand < cnt && w2[cand] > 0.f) {
          float xv = w2[cand];
          int cgt = 0, cge = 0;
          #pragma unroll
          for (int j2 = 0; j2 < 8; ++j2)
            if (j2 < cnt && w2[j2] > 0.f) { cgt += (w2[j2] > xv); cge += (w2[j2] >= xv); }
          if (cgt <= rankj && rankj < cge) wnj = xv;
        }
      }
    }
    if (lane < cnt) mb[(size_t)myk*HW + p] = wnj;   // dense updates
    if (lane < 8)  { wnL[lane] = wnj; kL[lane] = myk; }
    __syncthreads();

    if (lane == 0) {
      // merge original compact (asc k) with near-color updates
      int on = 0, ii = 0, jj = 0;
      while (ii < 16 || jj < cnt) {
        if (ii < 16 && wOrigL[ii] <= 0.f) { ++ii; continue; }
        int ko = (ii < 16) ? kOrigL[ii] : (1 << 20);
        int kj = (jj < cnt) ? kL[jj] : (1 << 20);
        if (ko >= (1 << 20) && kj >= (1 << 20)) break;
        if (ko < kj) {
          if (on < 16) { cb_[on] = (unsigned char)ko; cwp[on] = wOrigL[ii]; ++on; }
          ++ii;
        } else if (kj < ko) {
          if (wnL[jj] > 0.f && on < 16) { cb_[on] = (unsigned char)kj; cwp[on] = wnL[jj]; ++on; }
          ++jj;
        } else {
          if (wnL[jj] > 0.f && on < 16) { cb_[on] = (unsigned char)kj; cwp[on] = wnL[jj]; ++on; }
          ++ii; ++jj;
        }
      }
      for (int j = on; j < 16; ++j) { cb_[j] = 0; cwp[j] = 0.f; }
    }
    __syncthreads();
  }
}

// ---------------- K3: num/den accumulation -----------------------------------

__global__ __launch_bounds__(256) void k3_accum(
    const uint4* __restrict__ cidx, const float4* __restrict__ cw4,
    const float* __restrict__ img, float* __restrict__ part)
{
  __shared__ float acc[1024];
  const int t = threadIdx.x, blk = blockIdx.x;
  for (int i = t; i < 1024; i += 256) acc[i] = 0.f;
  __syncthreads();
  const int b = blk / 144;
  const int p = (blk % 144) * 256 + t;
  const float* imb = img + (size_t)b*3*HW;
  const int g = b*HW + p;
  uint4 iv = cidx[g];
  unsigned ivq[4] = {iv.x, iv.y, iv.z, iv.w};
  float r = imb[p], g_ = imb[HW + p], bl = imb[2*HW + p];
  #pragma unroll
  for (int q = 0; q < 4; ++q) {
    float4 wv = cw4[(size_t)g*4 + q];
    float wvv[4] = {wv.x, wv.y, wv.z, wv.w};
    #pragma unroll
    for (int u = 0; u < 4; ++u) {
      int k = (int)((ivq[q] >> (8*u)) & 255u);
      float wgt = wvv[u];
      atomicAdd(&acc[k],       wgt * r);
      atomicAdd(&acc[256 + k], wgt * g_);
      atomicAdd(&acc[512 + k], wgt * bl);
      atomicAdd(&acc[768 + k], wgt);
    }
  }
  __syncthreads();
  for (int i = t; i < 1024; i += 256) part[(size_t)blk*1024 + i] = acc[i];
}

// ---------------- K4: palette ------------------------------------------------

__global__ __launch_bounds__(256) void k4_pal(
    const float* __restrict__ part, float* __restrict__ out_pal)
{
  __shared__ float acc[1024];
  const int b = blockIdx.x, t = threadIdx.x;
  for (int s = t; s < 1024; s += 256) {
    float a = 0.f;
    for (int i = 0; i < 144; ++i) a += part[(size_t)(b*144 + i)*1024 + s];
    acc[s] = a;
  }
  __syncthreads();
  for (int s = t; s < 768; s += 256) {
    int k = s & 255;
    float den = acc[768 + k] + 1e-8f;
    out_pal[(size_t)b*768 + s] = acc[s] / den;
  }
}

// ---------------- K5: recolored image ----------------------------------------

__global__ __launch_bounds__(256) void k5_img(
    const uint4* __restrict__ cidx, const float4* __restrict__ cw4,
    const float* __restrict__ pal, float* __restrict__ outimg)
{
  __shared__ float lp[768];
  const int t = threadIdx.x, blk = blockIdx.x;
  const int b = blk / 144;
  for (int i = t; i < 768; i += 256) lp[i] = pal[(size_t)b*768 + i];
  __syncthreads();
  const int p = (blk % 144) * 256 + t;
  const int g = b*HW + p;
  uint4 iv = cidx[g];
  unsigned ivq[4] = {iv.x, iv.y, iv.z, iv.w};
  float r = 0.f, g_ = 0.f, bl = 0.f;
  #pragma unroll
  for (int q = 0; q < 4; ++q) {
    float4 wv = cw4[(size_t)g*4 + q];
    float wvv[4] = {wv.x, wv.y, wv.z, wv.w};
    #pragma unroll
    for (int u = 0; u < 4; ++u) {
      int k = (int)((ivq[q] >> (8*u)) & 255u);
      float wgt = wvv[u];
      r  = fmaf(wgt, lp[k],       r);
      g_ = fmaf(wgt, lp[256 + k], g_);
      bl = fmaf(wgt, lp[512 + k], bl);
    }
  }
  float* ob = outimg + (size_t)b*3*HW;
  ob[p] = r; ob[HW + p] = g_; ob[2*HW + p] = bl;
}

// ---------------- launcher ---------------------------------------------------

extern "C" void kernel_launch(void* const* d_in, const int* in_sizes, int n_in,
                              void* d_out, int out_size, void* d_ws, size_t ws_size,
                              hipStream_t stream)
{
  const float* img   = (const float*)d_in[0];
  const float* bfeat = (const float*)d_in[1];
  const float* wb    = (const float*)d_in[2];
  const float* bb    = (const float*)d_in[3];
  const float* gam   = (const float*)d_in[4];
  const float* bet   = (const float*)d_in[5];
  const float* wm    = (const float*)d_in[6];

  float* out_img = (float*)d_out;                 // [4,3,192,192]
  float* out_msp = (float*)d_out + 442368;        // [4,256,192,192]
  float* out_pal = (float*)d_out + 38191104;      // [4,3,256,1,1]

  char* w = (char*)d_ws;
  float*     ws_x       = (float*)(w);                     // 9,437,184 B (dead after k2 -> reused for k3 partials)
  double*    ws_part    = (double*)(w + 9437184);          //   147,456 B
  double*    ws_st64    = (double*)(w + 9584640);          //       256 B
  float*     ws_st32    = (float*)(w + 9584896);           //       128 B
  unsigned*  ws_flagcnt = (unsigned*)(w + 9585152);        //       256 B pad
  FlagEntry* ws_entries = (FlagEntry*)(w + 9585408);       // 2,359,296 B
  unsigned*  ws_cidx    = (unsigned*)(w + 11944704);       // 2,359,296 B
  float*     ws_cw      = (float*)(w + 14304000);          // 9,437,184 B
  float*     ws_nd      = ws_x;                            // aliases ws_x (x dead after k2)
  short*     ws_bfrag   = (short*)(w + 23741184);          //    32,768 B

  k0_zero<<<dim3(1), dim3(1), 0, stream>>>(ws_flagcnt);
  k1_conv<<<dim3(576), dim3(256), 0, stream>>>(bfeat, wb, bb, ws_x, ws_part);
  k1b_stats<<<dim3(1), dim3(64), 0, stream>>>(ws_part, gam, bet, ws_st64, ws_st32);
  k1c_bfrag<<<dim3(1), dim3(256), 0, stream>>>(wm, ws_bfrag);
  k2_main<<<dim3(2304), dim3(256), 72192, stream>>>(ws_x, ws_bfrag, ws_st32, out_msp,
                                                    ws_cidx, ws_cw, ws_flagcnt, ws_entries);
  k2b_fix<<<dim3(4096), dim3(64), 0, stream>>>(bfeat, wb, bb, wm, ws_st64,
                                               ws_flagcnt, ws_entries, out_msp, ws_cidx, ws_cw);
  k3_accum<<<dim3(576), dim3(256), 0, stream>>>((const uint4*)ws_cidx, (const float4*)ws_cw,
                                                img, ws_nd);
  k4_pal<<<dim3(4), dim3(256), 0, stream>>>(ws_nd, out_pal);
  k5_img<<<dim3(576), dim3(256), 0, stream>>>((const uint4*)ws_cidx, (const float4*)ws_cw,
                                              out_pal, out_img);
}